// Round 1
// baseline (752.539 us; speedup 1.0000x reference)
//
#include <hip/hip_runtime.h>
#include <math.h>

#define BB   128   // batch
#define WW   128   // window
#define FIN  64
#define NNODE 64
#define NE   4096
#define EDIM 16
#define NH   4
#define CDIM 32
#define HC   128   // NH*CDIM
#define FLATD 8192
#define HIDD 2048

// ws layout (float offsets)
#define OFF_H    0u         // h[B][64][128]           1,048,576 f
#define OFF_SC   1048576u   // score[B][E][4]          2,097,152 f
#define OFF_M    3145728u   // m[B][64][4] (uint)         32,768
#define OFF_DEN  3178496u   // den[B][64][4]              32,768
#define OFF_XG   3211264u   // xgat_pre[B][8192]       1,048,576
#define OFF_H1   4259840u   // h1raw[B][2048]            262,144
// total 4,521,984 floats = 18.1 MB

__device__ __forceinline__ unsigned ordf(float x) {
    unsigned u = __float_as_uint(x);
    return (u & 0x80000000u) ? ~u : (u | 0x80000000u);
}
__device__ __forceinline__ float unordf(unsigned u) {
    return (u & 0x80000000u) ? __uint_as_float(u ^ 0x80000000u) : __uint_as_float(~u);
}

__device__ __forceinline__ void load16(const float* p, float* dst) {
    const float4* q = (const float4*)p;
#pragma unroll
    for (int i = 0; i < 4; ++i) {
        float4 v = q[i];
        dst[i*4+0] = v.x; dst[i*4+1] = v.y; dst[i*4+2] = v.z; dst[i*4+3] = v.w;
    }
}

// ---------------- K1: TCN conv1d(k=3,pad=1) + lin_l -> h[b][n][o] ----------------
// grid (128 b, 2 n-halves), 256 threads
__global__ __launch_bounds__(256) void k1_tcn_linl(
        const float* __restrict__ x, const float* __restrict__ tcn_w,
        const float* __restrict__ tcn_b, const float* __restrict__ lin_l_w,
        const float* __restrict__ lin_l_b, float* __restrict__ h)
{
    __shared__ float xs[130*65];   // [padded w(0..129)][i], rows 0/129 = zero pad
    __shared__ float xg[32*129];   // [n_local][w]
    const int b = blockIdx.x, half = blockIdx.y, t = threadIdx.x;
    const int n0 = half * 32;

    for (int idx = t; idx < 8192; idx += 256) {
        int w = idx >> 6, i = idx & 63;
        xs[(w+1)*65 + i] = x[b*8192 + idx];
    }
    if (t < 65) { xs[t] = 0.f; xs[129*65 + t] = 0.f; }
    __syncthreads();

    // phase 1: conv. thread -> (n_local = t>>3, w-block of 16)
    {
        const int nl = t >> 3;
        const int n  = n0 + nl;
        const int w0 = (t & 7) * 16;
        float acc[16];
        const float tb = tcn_b[n];
#pragma unroll
        for (int j = 0; j < 16; ++j) acc[j] = tb;
        for (int i = 0; i < 64; ++i) {
            const float t0 = tcn_w[n*192 + 3*i + 0];
            const float t1 = tcn_w[n*192 + 3*i + 1];
            const float t2 = tcn_w[n*192 + 3*i + 2];
            float a = xs[(w0+0)*65 + i];
            float c0 = xs[(w0+1)*65 + i];
#pragma unroll
            for (int dw = 0; dw < 16; ++dw) {
                float c = xs[(w0+dw+2)*65 + i];
                acc[dw] += a*t0 + c0*t1 + c*t2;
                a = c0; c0 = c;
            }
        }
#pragma unroll
        for (int dw = 0; dw < 16; ++dw) xg[nl*129 + w0 + dw] = acc[dw];
    }
    __syncthreads();

    // phase 2: h[n][o] = sum_w xg[n][w]*lin_l_w[o][w] + lin_l_b[o]
    {
        const int o = t >> 1, ng = t & 1;
        float acc2[16];
        const float lb = lin_l_b[o];
#pragma unroll
        for (int j = 0; j < 16; ++j) acc2[j] = lb;
        for (int wc = 0; wc < 128; wc += 8) {
            float lw[8];
#pragma unroll
            for (int j = 0; j < 8; ++j) lw[j] = lin_l_w[o*128 + wc + j];
#pragma unroll
            for (int nn = 0; nn < 16; ++nn) {
#pragma unroll
                for (int j = 0; j < 8; ++j)
                    acc2[nn] += xg[(ng*16+nn)*129 + wc + j] * lw[j];
            }
        }
#pragma unroll
        for (int nn = 0; nn < 16; ++nn) {
            int n = n0 + ng*16 + nn;
            h[(b*64 + n)*128 + o] = acc2[nn];
        }
    }
}

// ---------------- K2a: edge scores + segment max ----------------
// grid (128 b, 4 edge-quarters), 256 threads, 4 edges/thread
__global__ __launch_bounds__(256) void k2a_scores(
        const float* __restrict__ hbase, const int* __restrict__ ei,
        const float* __restrict__ ea, const float* __restrict__ lin_e_w,
        const float* __restrict__ lin_e_b, const float* __restrict__ att,
        float* __restrict__ score, unsigned* __restrict__ mglob)
{
    __shared__ float hbuf[64*129];
    __shared__ float lew[128*20];
    __shared__ float leb[128];
    __shared__ float attv[128];
    __shared__ unsigned msh[256];
    const int b = blockIdx.x, q = blockIdx.y, t = threadIdx.x;

    for (int idx = t; idx < 8192; idx += 256)
        hbuf[(idx>>7)*129 + (idx&127)] = hbase[b*8192 + idx];
    for (int idx = t; idx < 2048; idx += 256)
        lew[(idx>>4)*20 + (idx&15)] = lin_e_w[idx];
    if (t < 128) { leb[t] = lin_e_b[t]; attv[t] = att[t]; }
    msh[t] = 0u;
    __syncthreads();

    const int e0 = q*1024 + t;
    int src[4], dst[4];
    float eav[4][16];
#pragma unroll
    for (int it = 0; it < 4; ++it) {
        int e = e0 + 256*it;
        src[it] = ei[e];
        dst[it] = ei[4096 + e];
        load16(ea + (size_t)(b*4096 + e)*16, eav[it]);
    }
    float sc[4][4];
#pragma unroll
    for (int it = 0; it < 4; ++it)
#pragma unroll
        for (int hh = 0; hh < 4; ++hh) sc[it][hh] = 0.f;

#pragma unroll
    for (int hh = 0; hh < 4; ++hh) {
        for (int oo = 0; oo < 32; ++oo) {
            const int o = hh*32 + oo;
            float lr[16];
            load16(lew + o*20, lr);
            const float lebo = leb[o], ao = attv[o];
#pragma unroll
            for (int it = 0; it < 4; ++it) {
                float ev = lebo;
#pragma unroll
                for (int d = 0; d < 16; ++d) ev += eav[it][d] * lr[d];
                float xv = hbuf[dst[it]*129 + o] + hbuf[src[it]*129 + o] + ev;
                float a = xv > 0.f ? xv : 0.01f * xv;
                sc[it][hh] += a * ao;
            }
        }
    }
#pragma unroll
    for (int it = 0; it < 4; ++it) {
        int e = e0 + 256*it;
        *(float4*)(score + (size_t)(b*4096 + e)*4) =
            make_float4(sc[it][0], sc[it][1], sc[it][2], sc[it][3]);
#pragma unroll
        for (int hh = 0; hh < 4; ++hh)
            atomicMax(&msh[dst[it]*4 + hh], ordf(sc[it][hh]));
    }
    __syncthreads();
    atomicMax(&mglob[b*256 + t], msh[t]);
}

// ---------------- K2b: ex = exp(score - m), segment sum ----------------
__global__ __launch_bounds__(256) void k2b_exp(
        const int* __restrict__ ei, float* __restrict__ score,
        const unsigned* __restrict__ mglob, float* __restrict__ denglob)
{
    __shared__ float dsh[256];
    const int b = blockIdx.x, q = blockIdx.y, t = threadIdx.x;
    dsh[t] = 0.f;
    __syncthreads();
    const int e0 = q*1024 + t;
#pragma unroll
    for (int it = 0; it < 4; ++it) {
        int e = e0 + 256*it;
        int dd = ei[4096 + e];
        float4 s4 = *(const float4*)(score + (size_t)(b*4096 + e)*4);
        uint4 m4 = *(const uint4*)(mglob + b*256 + dd*4);
        float e0v = expf(s4.x - unordf(m4.x));
        float e1v = expf(s4.y - unordf(m4.y));
        float e2v = expf(s4.z - unordf(m4.z));
        float e3v = expf(s4.w - unordf(m4.w));
        *(float4*)(score + (size_t)(b*4096 + e)*4) = make_float4(e0v, e1v, e2v, e3v);
        atomicAdd(&dsh[dd*4+0], e0v);
        atomicAdd(&dsh[dd*4+1], e1v);
        atomicAdd(&dsh[dd*4+2], e2v);
        atomicAdd(&dsh[dd*4+3], e3v);
    }
    __syncthreads();
    atomicAdd(&denglob[b*256 + t], dsh[t]);
}

// ---------------- K2c: alpha-weighted aggregation ----------------
__global__ __launch_bounds__(256) void k2c_aggregate(
        const float* __restrict__ hbase, const int* __restrict__ ei,
        const float* __restrict__ score, const float* __restrict__ denglob,
        float* __restrict__ xgat)
{
    __shared__ float acc[64*129];
    const int b = blockIdx.x, q = blockIdx.y, t = threadIdx.x;
    for (int idx = t; idx < 64*129; idx += 256) acc[idx] = 0.f;
    __syncthreads();
    const int e0 = q*1024 + t;
#pragma unroll
    for (int it = 0; it < 4; ++it) {
        int e = e0 + 256*it;
        int ss = ei[e], dd = ei[4096 + e];
        float4 ex4 = *(const float4*)(score + (size_t)(b*4096 + e)*4);
        float4 dn4 = *(const float4*)(denglob + b*256 + dd*4);
        float al[4] = { ex4.x/(dn4.x+1e-16f), ex4.y/(dn4.y+1e-16f),
                        ex4.z/(dn4.z+1e-16f), ex4.w/(dn4.w+1e-16f) };
        const float4* hs = (const float4*)(hbase + (size_t)(b*64 + ss)*128);
#pragma unroll
        for (int o4 = 0; o4 < 32; ++o4) {
            float4 hv = hs[o4];
            float a = al[o4 >> 3];
            int base = dd*129 + o4*4;
            atomicAdd(&acc[base+0], hv.x*a);
            atomicAdd(&acc[base+1], hv.y*a);
            atomicAdd(&acc[base+2], hv.z*a);
            atomicAdd(&acc[base+3], hv.w*a);
        }
    }
    __syncthreads();
    for (int idx = t; idx < 8192; idx += 256)
        atomicAdd(&xgat[(size_t)b*8192 + idx], acc[(idx>>7)*129 + (idx&127)]);
}

// ---------------- K3: fc1 GEMM (elu applied on load), k-split partials ----------------
// grid (16 j-blocks of 128, 16 k-splits of 512), 256 threads, 8b x 8j per thread
__global__ __launch_bounds__(256) void k3_fc1(
        const float* __restrict__ xgat, const float* __restrict__ fc1_w,
        float* __restrict__ h1)
{
    __shared__ float xs[32*129];    // [k][b]
    __shared__ float wsl[128*33];   // [j][k]
    const int jb = blockIdx.x, ks = blockIdx.y, t = threadIdx.x;
    const int j0 = jb*128, k0 = ks*512;
    const int bt = t & 15, jt = t >> 4;
    float acc[8][8];
#pragma unroll
    for (int i = 0; i < 8; ++i)
#pragma unroll
        for (int j = 0; j < 8; ++j) acc[i][j] = 0.f;

    for (int kc = 0; kc < 512; kc += 32) {
        __syncthreads();
        for (int idx = t; idx < 4096; idx += 256) {
            int k = idx & 31, bi = idx >> 5;
            float v = xgat[(size_t)bi*8192 + k0 + kc + k];
            v = v > 0.f ? v : expm1f(v);   // ELU
            xs[k*129 + bi] = v;
        }
        for (int idx = t; idx < 4096; idx += 256) {
            int k = idx & 31, j = idx >> 5;
            wsl[j*33 + k] = fc1_w[(size_t)(j0 + j)*8192 + k0 + kc + k];
        }
        __syncthreads();
        for (int k = 0; k < 32; ++k) {
            float xv[8], wv[8];
#pragma unroll
            for (int i = 0; i < 8; ++i) xv[i] = xs[k*129 + bt + 16*i];
#pragma unroll
            for (int j = 0; j < 8; ++j) wv[j] = wsl[(jt + 16*j)*33 + k];
#pragma unroll
            for (int i = 0; i < 8; ++i)
#pragma unroll
                for (int j = 0; j < 8; ++j) acc[i][j] += xv[i] * wv[j];
        }
    }
#pragma unroll
    for (int i = 0; i < 8; ++i) {
        int bi = bt + 16*i;
#pragma unroll
        for (int j = 0; j < 8; ++j) {
            int jj = j0 + jt + 16*j;
            atomicAdd(&h1[(size_t)bi*2048 + jj], acc[i][j]);
        }
    }
}

// ---------------- K4: bias+BN+relu + fc2 ----------------
__global__ __launch_bounds__(256) void k4_fc2(
        const float* __restrict__ h1, const float* __restrict__ fc1_b,
        const float* __restrict__ bn_g, const float* __restrict__ bn_b,
        const float* __restrict__ fc2_w, const float* __restrict__ fc2_b,
        float* __restrict__ out)
{
    __shared__ float r0[256], r1[256];
    const int b = blockIdx.x, t = threadIdx.x;
    const float inv = 1.0f / sqrtf(1.0f + 1e-5f);
    float p0 = 0.f, p1 = 0.f;
    for (int j = t; j < 2048; j += 256) {
        float hv = h1[(size_t)b*2048 + j];
        float v = (hv + fc1_b[j]) * (bn_g[j] * inv) + bn_b[j];
        v = fmaxf(v, 0.f);
        p0 += v * fc2_w[j];
        p1 += v * fc2_w[2048 + j];
    }
    r0[t] = p0; r1[t] = p1;
    __syncthreads();
    for (int s = 128; s > 0; s >>= 1) {
        if (t < s) { r0[t] += r0[t+s]; r1[t] += r1[t+s]; }
        __syncthreads();
    }
    if (t == 0) {
        out[b*2 + 0] = r0[0] + fc2_b[0];
        out[b*2 + 1] = r1[0] + fc2_b[1];
    }
}

extern "C" void kernel_launch(void* const* d_in, const int* in_sizes, int n_in,
                              void* d_out, int out_size, void* d_ws, size_t ws_size,
                              hipStream_t stream)
{
    const float* x       = (const float*)d_in[0];
    const int*   ei      = (const int*)  d_in[1];
    const float* ea      = (const float*)d_in[2];
    const float* tcn_w   = (const float*)d_in[3];
    const float* tcn_b   = (const float*)d_in[4];
    const float* lin_l_w = (const float*)d_in[5];
    const float* lin_l_b = (const float*)d_in[6];
    const float* lin_e_w = (const float*)d_in[7];
    const float* lin_e_b = (const float*)d_in[8];
    const float* att     = (const float*)d_in[9];
    const float* fc1_w   = (const float*)d_in[10];
    const float* fc1_b   = (const float*)d_in[11];
    const float* bn_g    = (const float*)d_in[12];
    const float* bn_b    = (const float*)d_in[13];
    const float* fc2_w   = (const float*)d_in[14];
    const float* fc2_b   = (const float*)d_in[15];

    float* ws     = (float*)d_ws;
    float* hbuf   = ws + OFF_H;
    float* score  = ws + OFF_SC;
    unsigned* m   = (unsigned*)(ws + OFF_M);
    float* den    = ws + OFF_DEN;
    float* xgat   = ws + OFF_XG;
    float* h1     = ws + OFF_H1;
    float* out    = (float*)d_out;

    hipMemsetAsync(m,    0, (size_t)BB*256*4, stream);
    hipMemsetAsync(den,  0, (size_t)BB*256*4, stream);
    hipMemsetAsync(xgat, 0, (size_t)BB*8192*4, stream);
    hipMemsetAsync(h1,   0, (size_t)BB*2048*4, stream);

    k1_tcn_linl<<<dim3(BB, 2), 256, 0, stream>>>(x, tcn_w, tcn_b, lin_l_w, lin_l_b, hbuf);
    k2a_scores<<<dim3(BB, 4), 256, 0, stream>>>(hbuf, ei, ea, lin_e_w, lin_e_b, att, score, m);
    k2b_exp<<<dim3(BB, 4), 256, 0, stream>>>(ei, score, m, den);
    k2c_aggregate<<<dim3(BB, 4), 256, 0, stream>>>(hbuf, ei, score, den, xgat);
    k3_fc1<<<dim3(16, 16), 256, 0, stream>>>(xgat, fc1_w, h1);
    k4_fc2<<<BB, 256, 0, stream>>>(h1, fc1_b, bn_g, bn_b, fc2_w, fc2_b, out);
}

// Round 2
// 568.347 us; speedup vs baseline: 1.3241x; 1.3241x over previous
//
#include <hip/hip_runtime.h>
#include <math.h>

#define BB   128   // batch
#define WW   128   // window
#define FIN  64
#define NNODE 64
#define NE   4096
#define EDIM 16
#define NH   4
#define CDIM 32
#define HC   128   // NH*CDIM
#define FLATD 8192
#define HIDD 2048

// ws layout (float offsets)
#define OFF_H    0u         // h[B][64][128]            1,048,576 f   (dead after k2c)
#define OFF_SC   1048576u   // score[B][E][4]           2,097,152 f   (dead after k2c)
#define OFF_M    3145728u   // m[B][64][4]                 32,768 f
#define OFF_DEN  3178496u   // den[B][64][4]               32,768 f
#define OFF_XG   3211264u   // xgat_pre[B][8192]        1,048,576 f
#define OFF_P    0u         // fc1 partials [8][128][2048] 2,097,152 f (ALIASES h+score, used after k2c)
#define OFF_BK   4259840u   // bucket ints: bstart[65] then blist[4096]
// total ~17.1 MB

__device__ __forceinline__ void load16(const float* p, float* dst) {
    const float4* q = (const float4*)p;
#pragma unroll
    for (int i = 0; i < 4; ++i) {
        float4 v = q[i];
        dst[i*4+0] = v.x; dst[i*4+1] = v.y; dst[i*4+2] = v.z; dst[i*4+3] = v.w;
    }
}

// ---------------- K0: bucket edges by destination node (graph shared across batch) ----
__global__ __launch_bounds__(256) void k0_bucket(
        const int* __restrict__ ei, int* __restrict__ bstart, int* __restrict__ blist)
{
    __shared__ int cnt[64];
    __shared__ int cur[65];
    const int t = threadIdx.x;
    if (t < 64) cnt[t] = 0;
    __syncthreads();
    for (int e = t; e < NE; e += 256) atomicAdd(&cnt[ei[NE + e]], 1);
    __syncthreads();
    if (t == 0) {
        int run = 0;
        for (int n = 0; n < 64; ++n) { cur[n] = run; run += cnt[n]; }
        cur[64] = run;
    }
    __syncthreads();
    if (t < 65) bstart[t] = cur[t];
    __syncthreads();
    for (int e = t; e < NE; e += 256) {
        int d = ei[NE + e], s = ei[e];
        int p = atomicAdd(&cur[d], 1);
        blist[p] = (e << 6) | s;           // pack edge id + src node
    }
}

// ---------------- K1: TCN conv1d(k=3,pad=1) + lin_l -> h[b][n][o] ----------------
__global__ __launch_bounds__(256) void k1_tcn_linl(
        const float* __restrict__ x, const float* __restrict__ tcn_w,
        const float* __restrict__ tcn_b, const float* __restrict__ lin_l_w,
        const float* __restrict__ lin_l_b, float* __restrict__ h)
{
    __shared__ float xs[130*65];
    __shared__ float xg[32*129];
    const int b = blockIdx.x, half = blockIdx.y, t = threadIdx.x;
    const int n0 = half * 32;

    for (int idx = t; idx < 8192; idx += 256) {
        int w = idx >> 6, i = idx & 63;
        xs[(w+1)*65 + i] = x[b*8192 + idx];
    }
    if (t < 65) { xs[t] = 0.f; xs[129*65 + t] = 0.f; }
    __syncthreads();

    {
        const int nl = t >> 3;
        const int n  = n0 + nl;
        const int w0 = (t & 7) * 16;
        float acc[16];
        const float tb = tcn_b[n];
#pragma unroll
        for (int j = 0; j < 16; ++j) acc[j] = tb;
        for (int i = 0; i < 64; ++i) {
            const float t0 = tcn_w[n*192 + 3*i + 0];
            const float t1 = tcn_w[n*192 + 3*i + 1];
            const float t2 = tcn_w[n*192 + 3*i + 2];
            float a = xs[(w0+0)*65 + i];
            float c0 = xs[(w0+1)*65 + i];
#pragma unroll
            for (int dw = 0; dw < 16; ++dw) {
                float c = xs[(w0+dw+2)*65 + i];
                acc[dw] += a*t0 + c0*t1 + c*t2;
                a = c0; c0 = c;
            }
        }
#pragma unroll
        for (int dw = 0; dw < 16; ++dw) xg[nl*129 + w0 + dw] = acc[dw];
    }
    __syncthreads();

    {
        const int o = t >> 1, ng = t & 1;
        float acc2[16];
        const float lb = lin_l_b[o];
#pragma unroll
        for (int j = 0; j < 16; ++j) acc2[j] = lb;
        for (int wc = 0; wc < 128; wc += 8) {
            float lw[8];
#pragma unroll
            for (int j = 0; j < 8; ++j) lw[j] = lin_l_w[o*128 + wc + j];
#pragma unroll
            for (int nn = 0; nn < 16; ++nn) {
#pragma unroll
                for (int j = 0; j < 8; ++j)
                    acc2[nn] += xg[(ng*16+nn)*129 + wc + j] * lw[j];
            }
        }
#pragma unroll
        for (int nn = 0; nn < 16; ++nn) {
            int n = n0 + ng*16 + nn;
            h[(b*64 + n)*128 + o] = acc2[nn];
        }
    }
}

// ---------------- K2a: edge scores (no atomics) ----------------
__global__ __launch_bounds__(256) void k2a_scores(
        const float* __restrict__ hbase, const int* __restrict__ ei,
        const float* __restrict__ ea, const float* __restrict__ lin_e_w,
        const float* __restrict__ lin_e_b, const float* __restrict__ att,
        float* __restrict__ score)
{
    __shared__ float hbuf[64*129];
    __shared__ float lew[128*20];
    __shared__ float leb[128];
    __shared__ float attv[128];
    const int b = blockIdx.x, q = blockIdx.y, t = threadIdx.x;

    for (int idx = t; idx < 8192; idx += 256)
        hbuf[(idx>>7)*129 + (idx&127)] = hbase[b*8192 + idx];
    for (int idx = t; idx < 2048; idx += 256)
        lew[(idx>>4)*20 + (idx&15)] = lin_e_w[idx];
    if (t < 128) { leb[t] = lin_e_b[t]; attv[t] = att[t]; }
    __syncthreads();

    const int e0 = q*1024 + t;
    int src[4], dst[4];
    float eav[4][16];
#pragma unroll
    for (int it = 0; it < 4; ++it) {
        int e = e0 + 256*it;
        src[it] = ei[e];
        dst[it] = ei[NE + e];
        load16(ea + (size_t)(b*NE + e)*16, eav[it]);
    }
    float sc[4][4];
#pragma unroll
    for (int it = 0; it < 4; ++it)
#pragma unroll
        for (int hh = 0; hh < 4; ++hh) sc[it][hh] = 0.f;

#pragma unroll
    for (int hh = 0; hh < 4; ++hh) {
        for (int oo = 0; oo < 32; ++oo) {
            const int o = hh*32 + oo;
            float lr[16];
            load16(lew + o*20, lr);
            const float lebo = leb[o], ao = attv[o];
#pragma unroll
            for (int it = 0; it < 4; ++it) {
                float ev = lebo;
#pragma unroll
                for (int d = 0; d < 16; ++d) ev += eav[it][d] * lr[d];
                float xv = hbuf[dst[it]*129 + o] + hbuf[src[it]*129 + o] + ev;
                float a = xv > 0.f ? xv : 0.01f * xv;
                sc[it][hh] += a * ao;
            }
        }
    }
#pragma unroll
    for (int it = 0; it < 4; ++it) {
        int e = e0 + 256*it;
        *(float4*)(score + (size_t)(b*NE + e)*4) =
            make_float4(sc[it][0], sc[it][1], sc[it][2], sc[it][3]);
    }
}

// ---------------- K2b: per-(b,n,h) max + sum(exp) via bucket gather (no atomics) ----
__global__ __launch_bounds__(256) void k2b_stats(
        const float* __restrict__ score, const int* __restrict__ bstart,
        const int* __restrict__ blist, float* __restrict__ mg, float* __restrict__ deng)
{
    const int b = blockIdx.x, t = threadIdx.x;
    const int n = t >> 2, hh = t & 3;
    const int s0 = bstart[n], s1 = bstart[n+1];
    float mx = -3.4e38f;
    for (int i = s0; i < s1; ++i) {
        int e = blist[i] >> 6;
        mx = fmaxf(mx, score[((size_t)b*NE + e)*4 + hh]);
    }
    if (s1 == s0) mx = 0.f;           // isfinite(m) -> 0 for empty segments
    float sum = 0.f;
    for (int i = s0; i < s1; ++i) {
        int e = blist[i] >> 6;
        sum += __expf(score[((size_t)b*NE + e)*4 + hh] - mx);
    }
    mg[b*256 + t] = mx;
    deng[b*256 + t] = sum;
}

// ---------------- K2c: aggregation via bucket gather (no atomics) ----------------
// grid (128 b, 2 node-halves), 256 threads; 32-lane group owns one node at a time.
__global__ __launch_bounds__(256) void k2c_aggregate(
        const float* __restrict__ hbase, const float* __restrict__ score,
        const float* __restrict__ mg, const float* __restrict__ deng,
        const int* __restrict__ bstart, const int* __restrict__ blist,
        float* __restrict__ xgat)
{
    __shared__ float hsh[64*128];     // stride 128: conflict-free for lane-contiguous b128
    __shared__ float msh[256], rdsh[256];
    __shared__ int   bls[4096];
    __shared__ int   bst[33];
    const int b = blockIdx.x, yy = blockIdx.y, t = threadIdx.x;

    for (int idx = t; idx < 8192; idx += 256) hsh[idx] = hbase[(size_t)b*8192 + idx];
    msh[t]  = mg[b*256 + t];
    rdsh[t] = 1.0f / (deng[b*256 + t] + 1e-16f);
    if (t < 33) bst[t] = bstart[yy*32 + t];
    __syncthreads();
    const int lo = bst[0], hi = bst[32];
    for (int idx = lo + t; idx < hi; idx += 256) bls[idx - lo] = blist[idx];
    __syncthreads();

    const int w = t >> 6, lane = t & 63, half = lane >> 5, li = lane & 31;
    const int hq = li >> 3;   // head = (li*4)/32
#pragma unroll
    for (int it = 0; it < 4; ++it) {
        const int nl = w*8 + it*2 + half;       // local node 0..31
        const int n  = yy*32 + nl;
        const float mh = msh[n*4 + hq];
        const float rd = rdsh[n*4 + hq];
        const int s0 = bst[nl] - lo, s1 = bst[nl+1] - lo;
        float4 acc = make_float4(0.f, 0.f, 0.f, 0.f);
        for (int i = s0; i < s1; ++i) {
            const int pk = bls[i];
            const int e = pk >> 6, ss = pk & 63;
            const float sc = score[((size_t)b*NE + e)*4 + hq];
            const float al = __expf(sc - mh) * rd;
            const float4 hv = *(const float4*)&hsh[ss*128 + li*4];
            acc.x += hv.x * al; acc.y += hv.y * al;
            acc.z += hv.z * al; acc.w += hv.w * al;
        }
        *(float4*)&xgat[(size_t)b*8192 + n*128 + li*4] = acc;
    }
}

// ---------------- K3: fc1 GEMM, split-k into disjoint partial buffers ----------------
// grid (32 j-blocks of 64, 8 k-splits of 1024), 256 threads, 8b x 4j per thread
__global__ __launch_bounds__(256) void k3_fc1(
        const float* __restrict__ xgat, const float* __restrict__ fc1_w,
        float* __restrict__ part)
{
    __shared__ float xs[32*129];    // [k][b]
    __shared__ float wsl[64*33];    // [j][k]
    const int jb = blockIdx.x, ks = blockIdx.y, t = threadIdx.x;
    const int j0 = jb*64, k0 = ks*1024;
    const int bt = t & 15, jt = t >> 4;
    float acc[8][4];
#pragma unroll
    for (int i = 0; i < 8; ++i)
#pragma unroll
        for (int j = 0; j < 4; ++j) acc[i][j] = 0.f;

    for (int kc = 0; kc < 1024; kc += 32) {
        __syncthreads();
        for (int idx = t; idx < 4096; idx += 256) {
            int k = idx & 31, bi = idx >> 5;
            float v = xgat[(size_t)bi*8192 + k0 + kc + k];
            v = v > 0.f ? v : expm1f(v);   // ELU
            xs[k*129 + bi] = v;
        }
        for (int idx = t; idx < 2048; idx += 256) {
            int k = idx & 31, j = idx >> 5;
            wsl[j*33 + k] = fc1_w[(size_t)(j0 + j)*8192 + k0 + kc + k];
        }
        __syncthreads();
        for (int k = 0; k < 32; ++k) {
            float xv[8], wv[4];
#pragma unroll
            for (int i = 0; i < 8; ++i) xv[i] = xs[k*129 + bt + 16*i];
#pragma unroll
            for (int j = 0; j < 4; ++j) wv[j] = wsl[(jt + 16*j)*33 + k];
#pragma unroll
            for (int i = 0; i < 8; ++i)
#pragma unroll
                for (int j = 0; j < 4; ++j) acc[i][j] += xv[i] * wv[j];
        }
    }
#pragma unroll
    for (int i = 0; i < 8; ++i) {
        const int bi = bt + 16*i;
#pragma unroll
        for (int j = 0; j < 4; ++j) {
            const int jj = j0 + jt + 16*j;
            part[(size_t)ks*262144 + (size_t)bi*2048 + jj] = acc[i][j];
        }
    }
}

// ---------------- K4: reduce partials + bias + BN + relu + fc2 ----------------
__global__ __launch_bounds__(256) void k4_fc2(
        const float* __restrict__ part, const float* __restrict__ fc1_b,
        const float* __restrict__ bn_g, const float* __restrict__ bn_b,
        const float* __restrict__ fc2_w, const float* __restrict__ fc2_b,
        float* __restrict__ out)
{
    __shared__ float r0[256], r1[256];
    const int b = blockIdx.x, t = threadIdx.x;
    const float inv = 1.0f / sqrtf(1.0f + 1e-5f);
    float p0 = 0.f, p1 = 0.f;
    for (int j = t; j < 2048; j += 256) {
        float hv = 0.f;
#pragma unroll
        for (int s = 0; s < 8; ++s) hv += part[(size_t)s*262144 + (size_t)b*2048 + j];
        float v = (hv + fc1_b[j]) * (bn_g[j] * inv) + bn_b[j];
        v = fmaxf(v, 0.f);
        p0 += v * fc2_w[j];
        p1 += v * fc2_w[2048 + j];
    }
    r0[t] = p0; r1[t] = p1;
    __syncthreads();
    for (int s = 128; s > 0; s >>= 1) {
        if (t < s) { r0[t] += r0[t+s]; r1[t] += r1[t+s]; }
        __syncthreads();
    }
    if (t == 0) {
        out[b*2 + 0] = r0[0] + fc2_b[0];
        out[b*2 + 1] = r1[0] + fc2_b[1];
    }
}

extern "C" void kernel_launch(void* const* d_in, const int* in_sizes, int n_in,
                              void* d_out, int out_size, void* d_ws, size_t ws_size,
                              hipStream_t stream)
{
    const float* x       = (const float*)d_in[0];
    const int*   ei      = (const int*)  d_in[1];
    const float* ea      = (const float*)d_in[2];
    const float* tcn_w   = (const float*)d_in[3];
    const float* tcn_b   = (const float*)d_in[4];
    const float* lin_l_w = (const float*)d_in[5];
    const float* lin_l_b = (const float*)d_in[6];
    const float* lin_e_w = (const float*)d_in[7];
    const float* lin_e_b = (const float*)d_in[8];
    const float* att     = (const float*)d_in[9];
    const float* fc1_w   = (const float*)d_in[10];
    const float* fc1_b   = (const float*)d_in[11];
    const float* bn_g    = (const float*)d_in[12];
    const float* bn_b    = (const float*)d_in[13];
    const float* fc2_w   = (const float*)d_in[14];
    const float* fc2_b   = (const float*)d_in[15];

    float* ws     = (float*)d_ws;
    float* hbuf   = ws + OFF_H;
    float* score  = ws + OFF_SC;
    float* m      = ws + OFF_M;
    float* den    = ws + OFF_DEN;
    float* xgat   = ws + OFF_XG;
    float* part   = ws + OFF_P;      // aliases h+score (dead by k3)
    int*   bstart = (int*)(ws + OFF_BK);
    int*   blist  = bstart + 80;     // 65 used, aligned pad
    float* out    = (float*)d_out;

    k0_bucket  <<<1, 256, 0, stream>>>(ei, bstart, blist);
    k1_tcn_linl<<<dim3(BB, 2), 256, 0, stream>>>(x, tcn_w, tcn_b, lin_l_w, lin_l_b, hbuf);
    k2a_scores <<<dim3(BB, 4), 256, 0, stream>>>(hbuf, ei, ea, lin_e_w, lin_e_b, att, score);
    k2b_stats  <<<BB, 256, 0, stream>>>(score, bstart, blist, m, den);
    k2c_aggregate<<<dim3(BB, 2), 256, 0, stream>>>(hbuf, score, m, den, bstart, blist, xgat);
    k3_fc1     <<<dim3(32, 8), 256, 0, stream>>>(xgat, fc1_w, part);
    k4_fc2     <<<BB, 256, 0, stream>>>(part, fc1_b, bn_g, bn_b, fc2_w, fc2_b, out);
}

// Round 3
// 351.875 us; speedup vs baseline: 2.1387x; 1.6152x over previous
//
#include <hip/hip_runtime.h>
#include <math.h>

#define BB   128   // batch
#define WW   128   // window
#define FIN  64
#define NNODE 64
#define NE   4096
#define EDIM 16
#define NH   4
#define CDIM 32
#define HC   128   // NH*CDIM
#define FLATD 8192
#define HIDD 2048

// ws layout (float offsets)
#define OFF_H    0u         // h[B][64][128]            1,048,576 f   (dead after k2c)
#define OFF_SC   1048576u   // score[B][E][4]           2,097,152 f   (dead after k2c)
#define OFF_M    3145728u   // pos[4096] ints live here (old m/den region)
#define OFF_XG   3211264u   // xgat_pre[B][8192]        1,048,576 f
#define OFF_P    0u         // fc1 partials [8][128][2048] 2,097,152 f (aliases h+score)
#define OFF_BK   4259840u   // bucket ints: bstart[65(pad 80)] then blist[4096]

typedef unsigned short u16;
typedef u16    u16x8  __attribute__((ext_vector_type(8)));
typedef __bf16 bf16x8 __attribute__((ext_vector_type(8)));
typedef float  f32x4  __attribute__((ext_vector_type(4)));

__device__ __forceinline__ u16 f2bf(float f) {   // RNE fp32 -> bf16 bits
    unsigned u = __float_as_uint(f);
    u += 0x7fffu + ((u >> 16) & 1u);
    return (u16)(u >> 16);
}

__device__ __forceinline__ void load16(const float* p, float* dst) {
    const float4* q = (const float4*)p;
#pragma unroll
    for (int i = 0; i < 4; ++i) {
        float4 v = q[i];
        dst[i*4+0] = v.x; dst[i*4+1] = v.y; dst[i*4+2] = v.z; dst[i*4+3] = v.w;
    }
}

// ---------------- K0: bucket edges by destination (graph shared across batch) ----
__global__ __launch_bounds__(256) void k0_bucket(
        const int* __restrict__ ei, int* __restrict__ bstart,
        int* __restrict__ blist, int* __restrict__ pos)
{
    __shared__ int cnt[64];
    __shared__ int cur[65];
    const int t = threadIdx.x;
    if (t < 64) cnt[t] = 0;
    __syncthreads();
    for (int e = t; e < NE; e += 256) atomicAdd(&cnt[ei[NE + e]], 1);
    __syncthreads();
    if (t == 0) {
        int run = 0;
        for (int n = 0; n < 64; ++n) { cur[n] = run; run += cnt[n]; }
        cur[64] = run;
    }
    __syncthreads();
    if (t < 65) bstart[t] = cur[t];
    __syncthreads();
    for (int e = t; e < NE; e += 256) {
        int d = ei[NE + e], s = ei[e];
        int p = atomicAdd(&cur[d], 1);
        blist[p] = (e << 6) | s;           // pack edge id + src node
        pos[e] = p;
    }
}

// ---------------- K1: TCN conv1d(k=3,pad=1) + lin_l -> h[b][n][o] ----------------
__global__ __launch_bounds__(256) void k1_tcn_linl(
        const float* __restrict__ x, const float* __restrict__ tcn_w,
        const float* __restrict__ tcn_b, const float* __restrict__ lin_l_w,
        const float* __restrict__ lin_l_b, float* __restrict__ h)
{
    __shared__ float xs[130*65];
    __shared__ float xg[32*129];
    const int b = blockIdx.x, half = blockIdx.y, t = threadIdx.x;
    const int n0 = half * 32;

    for (int idx = t; idx < 8192; idx += 256) {
        int w = idx >> 6, i = idx & 63;
        xs[(w+1)*65 + i] = x[b*8192 + idx];
    }
    if (t < 65) { xs[t] = 0.f; xs[129*65 + t] = 0.f; }
    __syncthreads();

    {
        const int nl = t >> 3;
        const int n  = n0 + nl;
        const int w0 = (t & 7) * 16;
        float acc[16];
        const float tb = tcn_b[n];
#pragma unroll
        for (int j = 0; j < 16; ++j) acc[j] = tb;
        for (int i = 0; i < 64; ++i) {
            const float t0 = tcn_w[n*192 + 3*i + 0];
            const float t1 = tcn_w[n*192 + 3*i + 1];
            const float t2 = tcn_w[n*192 + 3*i + 2];
            float a = xs[(w0+0)*65 + i];
            float c0 = xs[(w0+1)*65 + i];
#pragma unroll
            for (int dw = 0; dw < 16; ++dw) {
                float c = xs[(w0+dw+2)*65 + i];
                acc[dw] += a*t0 + c0*t1 + c*t2;
                a = c0; c0 = c;
            }
        }
#pragma unroll
        for (int dw = 0; dw < 16; ++dw) xg[nl*129 + w0 + dw] = acc[dw];
    }
    __syncthreads();

    {
        const int o = t >> 1, ng = t & 1;
        float acc2[16];
        const float lb = lin_l_b[o];
#pragma unroll
        for (int j = 0; j < 16; ++j) acc2[j] = lb;
        for (int wc = 0; wc < 128; wc += 8) {
            float lw[8];
#pragma unroll
            for (int j = 0; j < 8; ++j) lw[j] = lin_l_w[o*128 + wc + j];
#pragma unroll
            for (int nn = 0; nn < 16; ++nn) {
#pragma unroll
                for (int j = 0; j < 8; ++j)
                    acc2[nn] += xg[(ng*16+nn)*129 + wc + j] * lw[j];
            }
        }
#pragma unroll
        for (int nn = 0; nn < 16; ++nn) {
            int n = n0 + ng*16 + nn;
            h[(b*64 + n)*128 + o] = acc2[nn];
        }
    }
}

// ---------------- K2a: edge scores, written in bucket order ----------------
__global__ __launch_bounds__(256) void k2a_scores(
        const float* __restrict__ hbase, const int* __restrict__ ei,
        const float* __restrict__ ea, const float* __restrict__ lin_e_w,
        const float* __restrict__ lin_e_b, const float* __restrict__ att,
        const int* __restrict__ pos, float* __restrict__ score)
{
    __shared__ float hbuf[64*129];
    __shared__ float lew[128*20];
    __shared__ float leb[128];
    __shared__ float attv[128];
    const int b = blockIdx.x, q = blockIdx.y, t = threadIdx.x;

    for (int idx = t; idx < 8192; idx += 256)
        hbuf[(idx>>7)*129 + (idx&127)] = hbase[b*8192 + idx];
    for (int idx = t; idx < 2048; idx += 256)
        lew[(idx>>4)*20 + (idx&15)] = lin_e_w[idx];
    if (t < 128) { leb[t] = lin_e_b[t]; attv[t] = att[t]; }
    __syncthreads();

    const int e0 = q*1024 + t;
    int src[4], dst[4], pp[4];
    float eav[4][16];
#pragma unroll
    for (int it = 0; it < 4; ++it) {
        int e = e0 + 256*it;
        src[it] = ei[e];
        dst[it] = ei[NE + e];
        pp[it]  = pos[e];
        load16(ea + (size_t)(b*NE + e)*16, eav[it]);
    }
    float sc[4][4];
#pragma unroll
    for (int it = 0; it < 4; ++it)
#pragma unroll
        for (int hh = 0; hh < 4; ++hh) sc[it][hh] = 0.f;

#pragma unroll
    for (int hh = 0; hh < 4; ++hh) {
        for (int oo = 0; oo < 32; ++oo) {
            const int o = hh*32 + oo;
            float lr[16];
            load16(lew + o*20, lr);
            const float lebo = leb[o], ao = attv[o];
#pragma unroll
            for (int it = 0; it < 4; ++it) {
                float ev = lebo;
#pragma unroll
                for (int d = 0; d < 16; ++d) ev += eav[it][d] * lr[d];
                float xv = hbuf[dst[it]*129 + o] + hbuf[src[it]*129 + o] + ev;
                float a = xv > 0.f ? xv : 0.01f * xv;
                sc[it][hh] += a * ao;
            }
        }
    }
#pragma unroll
    for (int it = 0; it < 4; ++it) {
        *(float4*)(score + (size_t)(b*NE + pp[it])*4) =
            make_float4(sc[it][0], sc[it][1], sc[it][2], sc[it][3]);
    }
}

// ---------------- K2c: fused softmax-stats + aggregation (bucket-ordered scores) ----
// grid (128 b, 2 node-halves), 256 threads; 32-lane group owns a node per it.
__global__ __launch_bounds__(256) void k2c_aggregate(
        const float* __restrict__ hbase, const float* __restrict__ score,
        const int* __restrict__ bstart, const int* __restrict__ blist,
        float* __restrict__ xgat)
{
    __shared__ float hsh[64*128];     // stride 128: conflict-free lane-contiguous b128
    __shared__ int   bls[4096];
    __shared__ int   bst[33];
    const int b = blockIdx.x, yy = blockIdx.y, t = threadIdx.x;

    for (int idx = t; idx < 8192; idx += 256) hsh[idx] = hbase[(size_t)b*8192 + idx];
    if (t < 33) bst[t] = bstart[yy*32 + t];
    __syncthreads();
    const int lo = bst[0], hi = bst[32];
    for (int idx = lo + t; idx < hi; idx += 256) bls[idx - lo] = blist[idx];
    __syncthreads();

    const int w = t >> 6, lane = t & 63, half = lane >> 5, li = lane & 31;
    const int hq = li >> 3, sl = li & 7;
    const float* scb = score + (size_t)b*NE*4;
#pragma unroll
    for (int it = 0; it < 4; ++it) {
        const int nl = w*8 + it*2 + half;       // local node 0..31
        const int n  = yy*32 + nl;
        const int s0 = bst[nl], s1 = bst[nl+1];
        // pass A: segment max (split over the 8-lane subgroup)
        float mx = -3.4e38f;
        for (int i = s0 + sl; i < s1; i += 8) mx = fmaxf(mx, scb[i*4 + hq]);
        mx = fmaxf(mx, __shfl_xor(mx, 1));
        mx = fmaxf(mx, __shfl_xor(mx, 2));
        mx = fmaxf(mx, __shfl_xor(mx, 4));
        // pass B: denominator
        float den = 0.f;
        for (int i = s0 + sl; i < s1; i += 8) den += __expf(scb[i*4 + hq] - mx);
        den += __shfl_xor(den, 1);
        den += __shfl_xor(den, 2);
        den += __shfl_xor(den, 4);
        const float rd = 1.0f / (den + 1e-16f);
        // pass C: weighted aggregation, scale at the end
        float4 acc = make_float4(0.f, 0.f, 0.f, 0.f);
        for (int i = s0; i < s1; ++i) {
            const float ex = __expf(scb[i*4 + hq] - mx);
            const int ss = bls[i - lo] & 63;
            const float4 hv = *(const float4*)&hsh[ss*128 + li*4];
            acc.x += hv.x * ex; acc.y += hv.y * ex;
            acc.z += hv.z * ex; acc.w += hv.w * ex;
        }
        acc.x *= rd; acc.y *= rd; acc.z *= rd; acc.w *= rd;
        *(float4*)&xgat[(size_t)b*8192 + n*128 + li*4] = acc;
    }
}

// ---------------- K3: fc1 via bf16 MFMA, split-K into disjoint partials ----------
// grid (32 j-tiles of 64, 8 k-splits of 1024), 256 threads = 4 waves.
// Tile 128m x 64n, BK=64. LDS bf16 with stride 72 (2-way bank alias = free).
__global__ __launch_bounds__(256) void k3_fc1(
        const float* __restrict__ xgat, const float* __restrict__ fc1_w,
        float* __restrict__ part)
{
    __shared__ u16 Ash[128*72];
    __shared__ u16 Bsh[64*72];
    const int jb = blockIdx.x, ks = blockIdx.y, t = threadIdx.x;
    const int j0 = jb*64, k0 = ks*1024;
    const int wave = t >> 6, lane = t & 63;
    const int quad = lane >> 4, l16 = lane & 15;
    const int wm = (wave & 1) * 64, wn = (wave >> 1) * 32;

    f32x4 acc[4][2];
#pragma unroll
    for (int i = 0; i < 4; ++i)
#pragma unroll
        for (int j = 0; j < 2; ++j) acc[i][j] = (f32x4){0.f, 0.f, 0.f, 0.f};

    const int arow = t >> 1, acol = (t & 1) * 32;   // A: 128 rows x 64 k
    const int brow = t >> 2, bcol = (t & 3) * 16;   // B: 64 rows x 64 k

    for (int kc = 0; kc < 1024; kc += 64) {
        if (kc) __syncthreads();
        // stage A (xgat + ELU -> bf16)
        const float* ap = xgat + (size_t)arow*FLATD + k0 + kc + acol;
#pragma unroll
        for (int qq = 0; qq < 4; ++qq) {
            float4 v0 = *(const float4*)(ap + qq*8);
            float4 v1 = *(const float4*)(ap + qq*8 + 4);
            float e0 = v0.x > 0.f ? v0.x : expm1f(v0.x);
            float e1 = v0.y > 0.f ? v0.y : expm1f(v0.y);
            float e2 = v0.z > 0.f ? v0.z : expm1f(v0.z);
            float e3 = v0.w > 0.f ? v0.w : expm1f(v0.w);
            float e4 = v1.x > 0.f ? v1.x : expm1f(v1.x);
            float e5 = v1.y > 0.f ? v1.y : expm1f(v1.y);
            float e6 = v1.z > 0.f ? v1.z : expm1f(v1.z);
            float e7 = v1.w > 0.f ? v1.w : expm1f(v1.w);
            u16x8 u = { f2bf(e0), f2bf(e1), f2bf(e2), f2bf(e3),
                        f2bf(e4), f2bf(e5), f2bf(e6), f2bf(e7) };
            *(u16x8*)&Ash[arow*72 + acol + qq*8] = u;
        }
        // stage B (fc1_w -> bf16)
        const float* bp = fc1_w + (size_t)(j0 + brow)*FLATD + k0 + kc + bcol;
#pragma unroll
        for (int qq = 0; qq < 2; ++qq) {
            float4 v0 = *(const float4*)(bp + qq*8);
            float4 v1 = *(const float4*)(bp + qq*8 + 4);
            u16x8 u = { f2bf(v0.x), f2bf(v0.y), f2bf(v0.z), f2bf(v0.w),
                        f2bf(v1.x), f2bf(v1.y), f2bf(v1.z), f2bf(v1.w) };
            *(u16x8*)&Bsh[brow*72 + bcol + qq*8] = u;
        }
        __syncthreads();
#pragma unroll
        for (int kk = 0; kk < 64; kk += 32) {
            bf16x8 af[4], bfr[2];
#pragma unroll
            for (int i = 0; i < 4; ++i)
                af[i] = *(const bf16x8*)&Ash[(wm + i*16 + l16)*72 + kk + quad*8];
#pragma unroll
            for (int j = 0; j < 2; ++j)
                bfr[j] = *(const bf16x8*)&Bsh[(wn + j*16 + l16)*72 + kk + quad*8];
#pragma unroll
            for (int i = 0; i < 4; ++i)
#pragma unroll
                for (int j = 0; j < 2; ++j)
                    acc[i][j] = __builtin_amdgcn_mfma_f32_16x16x32_bf16(
                        af[i], bfr[j], acc[i][j], 0, 0, 0);
        }
    }
    // epilogue: D[row=quad*4+r (m), col=l16 (n)]  [m89-verified layout]
#pragma unroll
    for (int i = 0; i < 4; ++i) {
#pragma unroll
        for (int j = 0; j < 2; ++j) {
            const int n = j0 + wn + j*16 + l16;
#pragma unroll
            for (int r = 0; r < 4; ++r) {
                const int m = wm + i*16 + quad*4 + r;
                part[(size_t)ks*262144 + (size_t)m*HIDD + n] = acc[i][j][r];
            }
        }
    }
}

// ---------------- K4: reduce partials + bias + BN + relu + fc2 ----------------
__global__ __launch_bounds__(256) void k4_fc2(
        const float* __restrict__ part, const float* __restrict__ fc1_b,
        const float* __restrict__ bn_g, const float* __restrict__ bn_b,
        const float* __restrict__ fc2_w, const float* __restrict__ fc2_b,
        float* __restrict__ out)
{
    __shared__ float r0[256], r1[256];
    const int b = blockIdx.x, t = threadIdx.x;
    const float inv = 1.0f / sqrtf(1.0f + 1e-5f);
    float p0 = 0.f, p1 = 0.f;
    for (int j = t; j < 2048; j += 256) {
        float hv = 0.f;
#pragma unroll
        for (int s = 0; s < 8; ++s) hv += part[(size_t)s*262144 + (size_t)b*2048 + j];
        float v = (hv + fc1_b[j]) * (bn_g[j] * inv) + bn_b[j];
        v = fmaxf(v, 0.f);
        p0 += v * fc2_w[j];
        p1 += v * fc2_w[2048 + j];
    }
    r0[t] = p0; r1[t] = p1;
    __syncthreads();
    for (int s = 128; s > 0; s >>= 1) {
        if (t < s) { r0[t] += r0[t+s]; r1[t] += r1[t+s]; }
        __syncthreads();
    }
    if (t == 0) {
        out[b*2 + 0] = r0[0] + fc2_b[0];
        out[b*2 + 1] = r1[0] + fc2_b[1];
    }
}

extern "C" void kernel_launch(void* const* d_in, const int* in_sizes, int n_in,
                              void* d_out, int out_size, void* d_ws, size_t ws_size,
                              hipStream_t stream)
{
    const float* x       = (const float*)d_in[0];
    const int*   ei      = (const int*)  d_in[1];
    const float* ea      = (const float*)d_in[2];
    const float* tcn_w   = (const float*)d_in[3];
    const float* tcn_b   = (const float*)d_in[4];
    const float* lin_l_w = (const float*)d_in[5];
    const float* lin_l_b = (const float*)d_in[6];
    const float* lin_e_w = (const float*)d_in[7];
    const float* lin_e_b = (const float*)d_in[8];
    const float* att     = (const float*)d_in[9];
    const float* fc1_w   = (const float*)d_in[10];
    const float* fc1_b   = (const float*)d_in[11];
    const float* bn_g    = (const float*)d_in[12];
    const float* bn_b    = (const float*)d_in[13];
    const float* fc2_w   = (const float*)d_in[14];
    const float* fc2_b   = (const float*)d_in[15];

    float* ws     = (float*)d_ws;
    float* hbuf   = ws + OFF_H;
    float* score  = ws + OFF_SC;
    int*   pos    = (int*)(ws + OFF_M);
    float* xgat   = ws + OFF_XG;
    float* part   = ws + OFF_P;      // aliases h+score (dead by k3)
    int*   bstart = (int*)(ws + OFF_BK);
    int*   blist  = bstart + 80;
    float* out    = (float*)d_out;

    k0_bucket  <<<1, 256, 0, stream>>>(ei, bstart, blist, pos);
    k1_tcn_linl<<<dim3(BB, 2), 256, 0, stream>>>(x, tcn_w, tcn_b, lin_l_w, lin_l_b, hbuf);
    k2a_scores <<<dim3(BB, 4), 256, 0, stream>>>(hbuf, ei, ea, lin_e_w, lin_e_b, att, pos, score);
    k2c_aggregate<<<dim3(BB, 2), 256, 0, stream>>>(hbuf, score, bstart, blist, xgat);
    k3_fc1     <<<dim3(32, 8), 256, 0, stream>>>(xgat, fc1_w, part);
    k4_fc2     <<<BB, 256, 0, stream>>>(part, fc1_b, bn_g, bn_b, fc2_w, fc2_b, out);
}

// Round 4
// 320.885 us; speedup vs baseline: 2.3452x; 1.0966x over previous
//
#include <hip/hip_runtime.h>
#include <math.h>

#define BB   128   // batch
#define WW   128   // window
#define FIN  64
#define NNODE 64
#define NE   4096
#define EDIM 16
#define NH   4
#define CDIM 32
#define HC   128   // NH*CDIM
#define FLATD 8192
#define HIDD 2048

// ws layout (float offsets)
#define OFF_H    0u         // h[B][64][128]          1,048,576 f  (dead after k2c)
#define OFF_SC   1048576u   // score[B][E][4]         2,097,152 f  (dead after k2c)
#define OFF_P    1048576u   // fc1 partials [8][128][2048] = 2,097,152 f (aliases score)
#define OFF_M    3145728u   // pos[4096] ints
#define OFF_XGB  3211264u   // xgat bf16 (ELU applied) [B][8192] u16 = 524,288 f
#define OFF_BK   4259840u   // bucket ints: bstart[80] + blist[4096]
// max offset 4,264,016 f = 17.06 MB (within proven ws usage)

typedef unsigned short u16;
typedef u16    u16x8  __attribute__((ext_vector_type(8)));
typedef u16    u16x4  __attribute__((ext_vector_type(4)));
typedef __bf16 bf16x8 __attribute__((ext_vector_type(8)));
typedef float  f32x4  __attribute__((ext_vector_type(4)));

__device__ __forceinline__ u16 f2bf(float f) {   // RNE fp32 -> bf16 bits
    unsigned u = __float_as_uint(f);
    u += 0x7fffu + ((u >> 16) & 1u);
    return (u16)(u >> 16);
}

__device__ __forceinline__ void load16(const float* p, float* dst) {
    const float4* q = (const float4*)p;
#pragma unroll
    for (int i = 0; i < 4; ++i) {
        float4 v = q[i];
        dst[i*4+0] = v.x; dst[i*4+1] = v.y; dst[i*4+2] = v.z; dst[i*4+3] = v.w;
    }
}

// ---------------- K0: bucket edges by destination (graph shared across batch) ----
__global__ __launch_bounds__(256) void k0_bucket(
        const int* __restrict__ ei, int* __restrict__ bstart,
        int* __restrict__ blist, int* __restrict__ pos)
{
    __shared__ int cnt[64];
    __shared__ int cur[65];
    const int t = threadIdx.x;
    if (t < 64) cnt[t] = 0;
    __syncthreads();
    for (int e = t; e < NE; e += 256) atomicAdd(&cnt[ei[NE + e]], 1);
    __syncthreads();
    if (t == 0) {
        int run = 0;
        for (int n = 0; n < 64; ++n) { cur[n] = run; run += cnt[n]; }
        cur[64] = run;
    }
    __syncthreads();
    if (t < 65) bstart[t] = cur[t];
    __syncthreads();
    for (int e = t; e < NE; e += 256) {
        int d = ei[NE + e], s = ei[e];
        int p = atomicAdd(&cur[d], 1);
        blist[p] = (e << 6) | s;           // pack edge id + src node
        pos[e] = p;
    }
}

// ---------------- K1: TCN conv1d(k=3,pad=1) + lin_l -> h[b][n][o] ----------------
__global__ __launch_bounds__(256) void k1_tcn_linl(
        const float* __restrict__ x, const float* __restrict__ tcn_w,
        const float* __restrict__ tcn_b, const float* __restrict__ lin_l_w,
        const float* __restrict__ lin_l_b, float* __restrict__ h)
{
    __shared__ float xs[130*65];
    __shared__ float xg[32*132];   // stride 132: float4-aligned rows
    const int b = blockIdx.x, half = blockIdx.y, t = threadIdx.x;
    const int n0 = half * 32;

    for (int idx = t; idx < 8192; idx += 256) {
        int w = idx >> 6, i = idx & 63;
        xs[(w+1)*65 + i] = x[b*8192 + idx];
    }
    if (t < 65) { xs[t] = 0.f; xs[129*65 + t] = 0.f; }
    __syncthreads();

    {   // phase 1: conv
        const int nl = t >> 3;
        const int n  = n0 + nl;
        const int w0 = (t & 7) * 16;
        float acc[16];
        const float tb = tcn_b[n];
#pragma unroll
        for (int j = 0; j < 16; ++j) acc[j] = tb;
        for (int i = 0; i < 64; ++i) {
            const float t0 = tcn_w[n*192 + 3*i + 0];
            const float t1 = tcn_w[n*192 + 3*i + 1];
            const float t2 = tcn_w[n*192 + 3*i + 2];
            float a = xs[(w0+0)*65 + i];
            float c0 = xs[(w0+1)*65 + i];
#pragma unroll
            for (int dw = 0; dw < 16; ++dw) {
                float c = xs[(w0+dw+2)*65 + i];
                acc[dw] += a*t0 + c0*t1 + c*t2;
                a = c0; c0 = c;
            }
        }
#pragma unroll
        for (int dw = 0; dw < 16; ++dw) xg[nl*132 + w0 + dw] = acc[dw];
    }
    __syncthreads();

    {   // phase 2: h[n][o] = xg[n][:] . lin_l_w[o][:] + b  — 2 o x 8 n register tile
        const int o2 = t & 63, ng = t >> 6;
        const int oA = o2, oB = o2 + 64;
        float accA[8], accB[8];
        const float lbA = lin_l_b[oA], lbB = lin_l_b[oB];
#pragma unroll
        for (int j = 0; j < 8; ++j) { accA[j] = lbA; accB[j] = lbB; }
        for (int c = 0; c < 32; ++c) {
            const float4 lwA = *(const float4*)&lin_l_w[oA*128 + c*4];
            const float4 lwB = *(const float4*)&lin_l_w[oB*128 + c*4];
#pragma unroll
            for (int nn = 0; nn < 8; ++nn) {
                const float4 xv = *(const float4*)&xg[(ng*8+nn)*132 + c*4];
                accA[nn] += xv.x*lwA.x + xv.y*lwA.y + xv.z*lwA.z + xv.w*lwA.w;
                accB[nn] += xv.x*lwB.x + xv.y*lwB.y + xv.z*lwB.z + xv.w*lwB.w;
            }
        }
#pragma unroll
        for (int nn = 0; nn < 8; ++nn) {
            const int n = n0 + ng*8 + nn;
            h[(b*64 + n)*128 + oA] = accA[nn];
            h[(b*64 + n)*128 + oB] = accB[nn];
        }
    }
}

// ---------------- K2a: edge scores, o-groups of 4 (b128 LDS), bucket-order out ----
__global__ __launch_bounds__(256) void k2a_scores(
        const float* __restrict__ hbase, const int* __restrict__ ei,
        const float* __restrict__ ea, const float* __restrict__ lin_e_w,
        const float* __restrict__ lin_e_b, const float* __restrict__ att,
        const int* __restrict__ pos, float* __restrict__ score)
{
    __shared__ float hbuf[64*132];   // stride 132: float4-aligned
    __shared__ float lew[128*20];    // [o][16 + pad4]: row = 80 B (16-aligned)
    __shared__ float leb[128];
    __shared__ float attv[128];
    const int b = blockIdx.x, q = blockIdx.y, t = threadIdx.x;

    for (int idx = t; idx < 8192; idx += 256)
        hbuf[(idx>>7)*132 + (idx&127)] = hbase[b*8192 + idx];
    for (int idx = t; idx < 2048; idx += 256)
        lew[(idx>>4)*20 + (idx&15)] = lin_e_w[idx];
    if (t < 128) { leb[t] = lin_e_b[t]; attv[t] = att[t]; }
    __syncthreads();

    const int e0 = q*1024 + t;
    int src[4], dst[4], pp[4];
    float eav[4][16];
#pragma unroll
    for (int it = 0; it < 4; ++it) {
        int e = e0 + 256*it;
        src[it] = ei[e];
        dst[it] = ei[NE + e];
        pp[it]  = pos[e];
        load16(ea + (size_t)(b*NE + e)*16, eav[it]);
    }
    float sc[4][4];
#pragma unroll
    for (int it = 0; it < 4; ++it)
#pragma unroll
        for (int hh = 0; hh < 4; ++hh) sc[it][hh] = 0.f;

    for (int o4 = 0; o4 < 32; ++o4) {
        const int hh = o4 >> 3;
        float4 lr[4][4];
        float lb4[4], at4[4];
#pragma unroll
        for (int j = 0; j < 4; ++j) {
            const int o = o4*4 + j;
#pragma unroll
            for (int d4 = 0; d4 < 4; ++d4)
                lr[j][d4] = *(const float4*)&lew[o*20 + d4*4];
            lb4[j] = leb[o]; at4[j] = attv[o];
        }
#pragma unroll
        for (int it = 0; it < 4; ++it) {
            const float4 hd = *(const float4*)&hbuf[dst[it]*132 + o4*4];
            const float4 hs = *(const float4*)&hbuf[src[it]*132 + o4*4];
            float hv4[4] = { hd.x + hs.x, hd.y + hs.y, hd.z + hs.z, hd.w + hs.w };
#pragma unroll
            for (int j = 0; j < 4; ++j) {
                float ev = lb4[j];
#pragma unroll
                for (int d4 = 0; d4 < 4; ++d4) {
                    ev += eav[it][d4*4+0]*lr[j][d4].x + eav[it][d4*4+1]*lr[j][d4].y
                        + eav[it][d4*4+2]*lr[j][d4].z + eav[it][d4*4+3]*lr[j][d4].w;
                }
                float xv = hv4[j] + ev;
                float a = xv > 0.f ? xv : 0.01f * xv;
                sc[it][hh] += a * at4[j];
            }
        }
    }
#pragma unroll
    for (int it = 0; it < 4; ++it) {
        *(float4*)(score + (size_t)(b*NE + pp[it])*4) =
            make_float4(sc[it][0], sc[it][1], sc[it][2], sc[it][3]);
    }
}

// ---------------- K2c: fused softmax + aggregation + ELU + bf16 out --------------
__global__ __launch_bounds__(256) void k2c_aggregate(
        const float* __restrict__ hbase, const float* __restrict__ score,
        const int* __restrict__ bstart, const int* __restrict__ blist,
        u16* __restrict__ xgb)
{
    __shared__ float hsh[64*128];
    __shared__ int   bls[4096];
    __shared__ int   bst[33];
    const int b = blockIdx.x, yy = blockIdx.y, t = threadIdx.x;

    for (int idx = t; idx < 8192; idx += 256) hsh[idx] = hbase[(size_t)b*8192 + idx];
    if (t < 33) bst[t] = bstart[yy*32 + t];
    __syncthreads();
    const int lo = bst[0], hi = bst[32];
    for (int idx = lo + t; idx < hi; idx += 256) bls[idx - lo] = blist[idx];
    __syncthreads();

    const int w = t >> 6, lane = t & 63, half = lane >> 5, li = lane & 31;
    const int hq = li >> 3, sl = li & 7;
    const float* scb = score + (size_t)b*NE*4;
#pragma unroll
    for (int it = 0; it < 4; ++it) {
        const int nl = w*8 + it*2 + half;
        const int n  = yy*32 + nl;
        const int s0 = bst[nl], s1 = bst[nl+1];
        float mx = -3.4e38f;
        for (int i = s0 + sl; i < s1; i += 8) mx = fmaxf(mx, scb[i*4 + hq]);
        mx = fmaxf(mx, __shfl_xor(mx, 1));
        mx = fmaxf(mx, __shfl_xor(mx, 2));
        mx = fmaxf(mx, __shfl_xor(mx, 4));
        float den = 0.f;
        for (int i = s0 + sl; i < s1; i += 8) den += __expf(scb[i*4 + hq] - mx);
        den += __shfl_xor(den, 1);
        den += __shfl_xor(den, 2);
        den += __shfl_xor(den, 4);
        const float rd = 1.0f / (den + 1e-16f);
        float4 acc = make_float4(0.f, 0.f, 0.f, 0.f);
        for (int i = s0; i < s1; ++i) {
            const float ex = __expf(scb[i*4 + hq] - mx);
            const int ss = bls[i - lo] & 63;
            const float4 hv = *(const float4*)&hsh[ss*128 + li*4];
            acc.x += hv.x * ex; acc.y += hv.y * ex;
            acc.z += hv.z * ex; acc.w += hv.w * ex;
        }
        acc.x *= rd; acc.y *= rd; acc.z *= rd; acc.w *= rd;
        // ELU + bf16 (same math as before: ELU on fp32, then RNE round)
        float e0 = acc.x > 0.f ? acc.x : expm1f(acc.x);
        float e1 = acc.y > 0.f ? acc.y : expm1f(acc.y);
        float e2 = acc.z > 0.f ? acc.z : expm1f(acc.z);
        float e3 = acc.w > 0.f ? acc.w : expm1f(acc.w);
        u16x4 st = { f2bf(e0), f2bf(e1), f2bf(e2), f2bf(e3) };
        *(u16x4*)&xgb[(size_t)b*8192 + n*128 + li*4] = st;
    }
}

// ---------------- K3: fc1 via bf16 MFMA; A pre-ELU'd bf16; split-K partials ------
// grid (64 j-tiles of 32, 8 k-splits of 1024), 256 threads = 4 waves, 2 blocks/CU.
__global__ __launch_bounds__(256) void k3_fc1(
        const u16* __restrict__ xgb, const float* __restrict__ fc1_w,
        float* __restrict__ part)
{
    __shared__ u16 Ash[128*72];
    __shared__ u16 Bsh[32*72];
    const int jb = blockIdx.x, ks = blockIdx.y, t = threadIdx.x;
    const int j0 = jb*32, k0 = ks*1024;
    const int wave = t >> 6, lane = t & 63;
    const int quad = lane >> 4, l16 = lane & 15;
    const int wm = (wave & 1) * 64, wn = (wave >> 1) * 16;

    f32x4 acc[4];
#pragma unroll
    for (int i = 0; i < 4; ++i) acc[i] = (f32x4){0.f, 0.f, 0.f, 0.f};

    const int arow = t >> 1, acol = (t & 1) * 32;   // A: 128 rows x 64 k (bf16 copy)
    const int brow = t >> 3, bcol = (t & 7) * 8;    // B: 32 rows x 64 k (fp32->bf16)

    for (int kc = 0; kc < 1024; kc += 64) {
        if (kc) __syncthreads();
        const u16* ap = xgb + (size_t)arow*FLATD + k0 + kc + acol;
#pragma unroll
        for (int qq = 0; qq < 4; ++qq)
            *(u16x8*)&Ash[arow*72 + acol + qq*8] = *(const u16x8*)(ap + qq*8);
        const float* bp = fc1_w + (size_t)(j0 + brow)*FLATD + k0 + kc + bcol;
        {
            float4 v0 = *(const float4*)(bp);
            float4 v1 = *(const float4*)(bp + 4);
            u16x8 u = { f2bf(v0.x), f2bf(v0.y), f2bf(v0.z), f2bf(v0.w),
                        f2bf(v1.x), f2bf(v1.y), f2bf(v1.z), f2bf(v1.w) };
            *(u16x8*)&Bsh[brow*72 + bcol] = u;
        }
        __syncthreads();
#pragma unroll
        for (int kk = 0; kk < 64; kk += 32) {
            bf16x8 af[4], bfr;
#pragma unroll
            for (int i = 0; i < 4; ++i)
                af[i] = *(const bf16x8*)&Ash[(wm + i*16 + l16)*72 + kk + quad*8];
            bfr = *(const bf16x8*)&Bsh[(wn + l16)*72 + kk + quad*8];
#pragma unroll
            for (int i = 0; i < 4; ++i)
                acc[i] = __builtin_amdgcn_mfma_f32_16x16x32_bf16(af[i], bfr, acc[i], 0, 0, 0);
        }
    }
    // epilogue: D[m = quad*4+r, n = l16]
#pragma unroll
    for (int i = 0; i < 4; ++i) {
        const int n = j0 + wn + l16;
#pragma unroll
        for (int r = 0; r < 4; ++r) {
            const int m = wm + i*16 + quad*4 + r;
            part[(size_t)ks*262144 + (size_t)m*HIDD + n] = acc[i][r];
        }
    }
}

// ---------------- K4: reduce partials + bias + BN + relu + fc2 ----------------
__global__ __launch_bounds__(256) void k4_fc2(
        const float* __restrict__ part, const float* __restrict__ fc1_b,
        const float* __restrict__ bn_g, const float* __restrict__ bn_b,
        const float* __restrict__ fc2_w, const float* __restrict__ fc2_b,
        float* __restrict__ out)
{
    __shared__ float r0[256], r1[256];
    const int b = blockIdx.x, t = threadIdx.x;
    const float inv = 1.0f / sqrtf(1.0f + 1e-5f);
    float p0 = 0.f, p1 = 0.f;
    for (int j = t; j < 2048; j += 256) {
        float hv = 0.f;
#pragma unroll
        for (int s = 0; s < 8; ++s) hv += part[(size_t)s*262144 + (size_t)b*2048 + j];
        float v = (hv + fc1_b[j]) * (bn_g[j] * inv) + bn_b[j];
        v = fmaxf(v, 0.f);
        p0 += v * fc2_w[j];
        p1 += v * fc2_w[2048 + j];
    }
    r0[t] = p0; r1[t] = p1;
    __syncthreads();
    for (int s = 128; s > 0; s >>= 1) {
        if (t < s) { r0[t] += r0[t+s]; r1[t] += r1[t+s]; }
        __syncthreads();
    }
    if (t == 0) {
        out[b*2 + 0] = r0[0] + fc2_b[0];
        out[b*2 + 1] = r1[0] + fc2_b[1];
    }
}

extern "C" void kernel_launch(void* const* d_in, const int* in_sizes, int n_in,
                              void* d_out, int out_size, void* d_ws, size_t ws_size,
                              hipStream_t stream)
{
    const float* x       = (const float*)d_in[0];
    const int*   ei      = (const int*)  d_in[1];
    const float* ea      = (const float*)d_in[2];
    const float* tcn_w   = (const float*)d_in[3];
    const float* tcn_b   = (const float*)d_in[4];
    const float* lin_l_w = (const float*)d_in[5];
    const float* lin_l_b = (const float*)d_in[6];
    const float* lin_e_w = (const float*)d_in[7];
    const float* lin_e_b = (const float*)d_in[8];
    const float* att     = (const float*)d_in[9];
    const float* fc1_w   = (const float*)d_in[10];
    const float* fc1_b   = (const float*)d_in[11];
    const float* bn_g    = (const float*)d_in[12];
    const float* bn_b    = (const float*)d_in[13];
    const float* fc2_w   = (const float*)d_in[14];
    const float* fc2_b   = (const float*)d_in[15];

    float* ws     = (float*)d_ws;
    float* hbuf   = ws + OFF_H;
    float* score  = ws + OFF_SC;
    float* part   = ws + OFF_P;          // aliases score (dead by k3)
    int*   pos    = (int*)(ws + OFF_M);
    u16*   xgb    = (u16*)(ws + OFF_XGB);
    int*   bstart = (int*)(ws + OFF_BK);
    int*   blist  = bstart + 80;
    float* out    = (float*)d_out;

    k0_bucket  <<<1, 256, 0, stream>>>(ei, bstart, blist, pos);
    k1_tcn_linl<<<dim3(BB, 2), 256, 0, stream>>>(x, tcn_w, tcn_b, lin_l_w, lin_l_b, hbuf);
    k2a_scores <<<dim3(BB, 4), 256, 0, stream>>>(hbuf, ei, ea, lin_e_w, lin_e_b, att, pos, score);
    k2c_aggregate<<<dim3(BB, 2), 256, 0, stream>>>(hbuf, score, bstart, blist, xgb);
    k3_fc1     <<<dim3(64, 8), 256, 0, stream>>>(xgb, fc1_w, part);
    k4_fc2     <<<BB, 256, 0, stream>>>(part, fc1_b, bn_g, bn_b, fc2_w, fc2_b, out);
}

// Round 6
// 256.090 us; speedup vs baseline: 2.9386x; 1.2530x over previous
//
#include <hip/hip_runtime.h>
#include <math.h>

#define BB   128   // batch
#define WW   128   // window
#define FIN  64
#define NNODE 64
#define NE   4096
#define EDIM 16
#define NH   4
#define CDIM 32
#define HC   128   // NH*CDIM
#define FLATD 8192
#define HIDD 2048

// ws layout (float offsets)
#define OFF_H    0u         // h[B][64][128]          1,048,576 f  (dead after k2c)
#define OFF_SC   1048576u   // score[B][E][4]         2,097,152 f  (dead after k2c)
#define OFF_P    1048576u   // fc1 partials [8][128][2048] = 2,097,152 f (aliases score)
#define OFF_M    3145728u   // pos[4096] ints
#define OFF_XGB  3211264u   // xgat bf16 (ELU applied) [B][8192] u16 = 524,288 f
#define OFF_BK   4259840u   // bucket ints: bstart[80] + blist[4096]

typedef unsigned short u16;
typedef u16    u16x8  __attribute__((ext_vector_type(8)));
typedef u16    u16x4  __attribute__((ext_vector_type(4)));
typedef __bf16 bf16x8 __attribute__((ext_vector_type(8)));
typedef float  f32x4  __attribute__((ext_vector_type(4)));
typedef float  f32x16 __attribute__((ext_vector_type(16)));

__device__ __forceinline__ u16 f2bf(float f) {   // RNE fp32 -> bf16 bits
    unsigned u = __float_as_uint(f);
    u += 0x7fffu + ((u >> 16) & 1u);
    return (u16)(u >> 16);
}
__device__ __forceinline__ void hilo(float v, u16* h, u16* l) {
    u16 hh = f2bf(v);
    float hf = __uint_as_float(((unsigned)hh) << 16);
    *h = hh;
    *l = f2bf(v - hf);
}

// ---------------- K0: bucket edges by destination (graph shared across batch) ----
__global__ __launch_bounds__(256) void k0_bucket(
        const int* __restrict__ ei, int* __restrict__ bstart,
        int* __restrict__ blist, int* __restrict__ pos)
{
    __shared__ int cnt[64];
    __shared__ int cur[65];
    const int t = threadIdx.x;
    if (t < 64) cnt[t] = 0;
    __syncthreads();
    for (int e = t; e < NE; e += 256) atomicAdd(&cnt[ei[NE + e]], 1);
    __syncthreads();
    if (t == 0) {
        int run = 0;
        for (int n = 0; n < 64; ++n) { cur[n] = run; run += cnt[n]; }
        cur[64] = run;
    }
    __syncthreads();
    if (t < 65) bstart[t] = cur[t];
    __syncthreads();
    for (int e = t; e < NE; e += 256) {
        int d = ei[NE + e], s = ei[e];
        int p = atomicAdd(&cur[d], 1);
        blist[p] = (e << 6) | s;           // pack edge id + src node
        pos[e] = p;
    }
}

// ---------------- K1: TCN conv1d(k=3,pad=1) + lin_l -> h[b][n][o] ----------------
__global__ __launch_bounds__(256) void k1_tcn_linl(
        const float* __restrict__ x, const float* __restrict__ tcn_w,
        const float* __restrict__ tcn_b, const float* __restrict__ lin_l_w,
        const float* __restrict__ lin_l_b, float* __restrict__ h)
{
    __shared__ float xs[130*65];
    __shared__ float xg[32*132];   // stride 132: float4-aligned rows
    const int b = blockIdx.x, half = blockIdx.y, t = threadIdx.x;
    const int n0 = half * 32;

    for (int idx = t; idx < 8192; idx += 256) {
        int w = idx >> 6, i = idx & 63;
        xs[(w+1)*65 + i] = x[b*8192 + idx];
    }
    if (t < 65) { xs[t] = 0.f; xs[129*65 + t] = 0.f; }
    __syncthreads();

    {   // phase 1: conv
        const int nl = t >> 3;
        const int n  = n0 + nl;
        const int w0 = (t & 7) * 16;
        float acc[16];
        const float tb = tcn_b[n];
#pragma unroll
        for (int j = 0; j < 16; ++j) acc[j] = tb;
        for (int i = 0; i < 64; ++i) {
            const float t0 = tcn_w[n*192 + 3*i + 0];
            const float t1 = tcn_w[n*192 + 3*i + 1];
            const float t2 = tcn_w[n*192 + 3*i + 2];
            float a = xs[(w0+0)*65 + i];
            float c0 = xs[(w0+1)*65 + i];
#pragma unroll
            for (int dw = 0; dw < 16; ++dw) {
                float c = xs[(w0+dw+2)*65 + i];
                acc[dw] += a*t0 + c0*t1 + c*t2;
                a = c0; c0 = c;
            }
        }
#pragma unroll
        for (int dw = 0; dw < 16; ++dw) xg[nl*132 + w0 + dw] = acc[dw];
    }
    __syncthreads();

    {   // phase 2: h[n][o] = xg[n][:] . lin_l_w[o][:] + b  — 2 o x 8 n register tile
        const int o2 = t & 63, ng = t >> 6;
        const int oA = o2, oB = o2 + 64;
        float accA[8], accB[8];
        const float lbA = lin_l_b[oA], lbB = lin_l_b[oB];
#pragma unroll
        for (int j = 0; j < 8; ++j) { accA[j] = lbA; accB[j] = lbB; }
        for (int c = 0; c < 32; ++c) {
            const float4 lwA = *(const float4*)&lin_l_w[oA*128 + c*4];
            const float4 lwB = *(const float4*)&lin_l_w[oB*128 + c*4];
#pragma unroll
            for (int nn = 0; nn < 8; ++nn) {
                const float4 xv = *(const float4*)&xg[(ng*8+nn)*132 + c*4];
                accA[nn] += xv.x*lwA.x + xv.y*lwA.y + xv.z*lwA.z + xv.w*lwA.w;
                accB[nn] += xv.x*lwB.x + xv.y*lwB.y + xv.z*lwB.z + xv.w*lwB.w;
            }
        }
#pragma unroll
        for (int nn = 0; nn < 8; ++nn) {
            const int n = n0 + ng*8 + nn;
            h[(b*64 + n)*128 + oA] = accA[nn];
            h[(b*64 + n)*128 + oB] = accB[nn];
        }
    }
}

// ---------------- K2a: edge scores via 32x32x16 bf16 MFMA (hi/lo fp32 emulation) --
// grid (128 b, 8 edge-eighths of 512), 256 threads = 4 waves; 128 edges/wave.
// A = lin_e_w (M=o), B = ea (N=edge). D: edge = lane&31, o = (reg&3)+8*(reg>>2)+4*(lane>>5).
__global__ __launch_bounds__(256, 2) void k2a_scores(
        const float* __restrict__ hbase, const int* __restrict__ ei,
        const float* __restrict__ ea, const float* __restrict__ lin_e_w,
        const float* __restrict__ lin_e_b, const float* __restrict__ att,
        const int* __restrict__ pos, float* __restrict__ score)
{
    __shared__ float hbuf[64*132];       // h + leb/2 folded; rows 16B-aligned
    __shared__ u16 eh[512*16];           // ea hi bf16
    __shared__ u16 el[512*16];           // ea lo bf16
    __shared__ int dsts[512], srcs[512], poss[512];
    const int b = blockIdx.x, q = blockIdx.y, t = threadIdx.x;
    const int e0 = q*512;
    const int lane = t & 63, wv = t >> 6, l32 = lane & 31, h5 = lane >> 5;

    for (int idx = t; idx < 8192; idx += 256) {
        const int o = idx & 127;
        hbuf[(idx>>7)*132 + o] = hbase[(size_t)b*8192 + idx] + 0.5f*lin_e_b[o];
    }
    for (int i4 = t; i4 < 2048; i4 += 256) {
        const int eL = i4 >> 2, d4 = (i4 & 3)*4;
        const float4 v = *(const float4*)&ea[((size_t)b*NE + e0 + eL)*16 + d4];
        u16 hh[4], ll[4];
        hilo(v.x,&hh[0],&ll[0]); hilo(v.y,&hh[1],&ll[1]);
        hilo(v.z,&hh[2],&ll[2]); hilo(v.w,&hh[3],&ll[3]);
        *(u16x4*)&eh[eL*16+d4] = (u16x4){hh[0],hh[1],hh[2],hh[3]};
        *(u16x4*)&el[eL*16+d4] = (u16x4){ll[0],ll[1],ll[2],ll[3]};
    }
    for (int e = t; e < 512; e += 256) {
        dsts[e] = ei[NE + e0 + e];
        srcs[e] = ei[e0 + e];
        poss[e] = pos[e0 + e];
    }
    // A-frags (lin_e_w rows = o) hi/lo and att — global reads into VGPRs
    bf16x8 Ah[4], Al[4];
#pragma unroll
    for (int mt = 0; mt < 4; ++mt) {
        const float* wp = &lin_e_w[(mt*32 + l32)*16 + h5*8];
        const float4 w0 = *(const float4*)wp;
        const float4 w1 = *(const float4*)(wp + 4);
        u16 th[8], tl[8];
        hilo(w0.x,&th[0],&tl[0]); hilo(w0.y,&th[1],&tl[1]);
        hilo(w0.z,&th[2],&tl[2]); hilo(w0.w,&th[3],&tl[3]);
        hilo(w1.x,&th[4],&tl[4]); hilo(w1.y,&th[5],&tl[5]);
        hilo(w1.z,&th[6],&tl[6]); hilo(w1.w,&th[7],&tl[7]);
        u16x8 vh = { th[0],th[1],th[2],th[3],th[4],th[5],th[6],th[7] };
        u16x8 vl = { tl[0],tl[1],tl[2],tl[3],tl[4],tl[5],tl[6],tl[7] };
        Ah[mt] = *(bf16x8*)&vh;
        Al[mt] = *(bf16x8*)&vl;
    }
    float4 attv[4][4];
#pragma unroll
    for (int mt = 0; mt < 4; ++mt)
#pragma unroll
        for (int g = 0; g < 4; ++g)
            attv[mt][g] = *(const float4*)&att[mt*32 + g*8 + h5*4];
    __syncthreads();

#pragma unroll
    for (int et = 0; et < 4; ++et) {
        const int edge = wv*128 + et*32 + l32;
        const int dd = dsts[edge], sn = srcs[edge];
        const bf16x8 Bh = *(const bf16x8*)&eh[edge*16 + h5*8];
        const bf16x8 Bl = *(const bf16x8*)&el[edge*16 + h5*8];
        float hacc[4];
#pragma unroll
        for (int mt = 0; mt < 4; ++mt) {
            f32x16 D = {0.f,0.f,0.f,0.f,0.f,0.f,0.f,0.f,
                        0.f,0.f,0.f,0.f,0.f,0.f,0.f,0.f};
            D = __builtin_amdgcn_mfma_f32_32x32x16_bf16(Al[mt], Bh, D, 0, 0, 0);
            D = __builtin_amdgcn_mfma_f32_32x32x16_bf16(Ah[mt], Bl, D, 0, 0, 0);
            D = __builtin_amdgcn_mfma_f32_32x32x16_bf16(Ah[mt], Bh, D, 0, 0, 0);
            float s = 0.f;
#pragma unroll
            for (int g = 0; g < 4; ++g) {
                const int ob = mt*32 + g*8 + h5*4;
                const float4 hd = *(const float4*)&hbuf[dd*132 + ob];
                const float4 hs = *(const float4*)&hbuf[sn*132 + ob];
                float x0 = hd.x + hs.x + D[g*4+0];
                float x1 = hd.y + hs.y + D[g*4+1];
                float x2 = hd.z + hs.z + D[g*4+2];
                float x3 = hd.w + hs.w + D[g*4+3];
                x0 = fmaxf(x0, 0.01f*x0); x1 = fmaxf(x1, 0.01f*x1);
                x2 = fmaxf(x2, 0.01f*x2); x3 = fmaxf(x3, 0.01f*x3);
                const float4 a4 = attv[mt][g];
                s += a4.x*x0 + a4.y*x1 + a4.z*x2 + a4.w*x3;
            }
            hacc[mt] = s;
        }
#pragma unroll
        for (int hh = 0; hh < 4; ++hh)
            hacc[hh] += __shfl_xor(hacc[hh], 32);
        if (h5 == 0)
            *(float4*)&score[((size_t)b*NE + poss[edge])*4] =
                make_float4(hacc[0], hacc[1], hacc[2], hacc[3]);
    }
}

// ---------------- K2c: softmax + aggregation, scores staged in LDS ---------------
// grid (128 b, 4 node-quarters), 256 threads, 2 blocks/CU.
#define CAP2C 2048
__global__ __launch_bounds__(256, 2) void k2c_aggregate(
        const float* __restrict__ hbase, const float* __restrict__ score,
        const int* __restrict__ bstart, const int* __restrict__ blist,
        u16* __restrict__ xgb)
{
    __shared__ float hsh[64*128];
    __shared__ float ssh[CAP2C*4];
    __shared__ int   bls[CAP2C];
    __shared__ int   bst[17];
    const int b = blockIdx.x, yy = blockIdx.y, t = threadIdx.x;

    for (int idx = t; idx < 8192; idx += 256) hsh[idx] = hbase[(size_t)b*8192 + idx];
    if (t < 17) bst[t] = bstart[yy*16 + t];
    __syncthreads();
    const int lo = bst[0], hi = bst[16];
    const int cnt = min(hi - lo, CAP2C);
    for (int i = t; i < cnt; i += 256) {
        *(float4*)&ssh[i*4] = *(const float4*)&score[((size_t)b*NE + lo + i)*4];
        bls[i] = blist[lo + i];
    }
    __syncthreads();

    const int w = t >> 6, lane = t & 63, half = lane >> 5, li = lane & 31;
    const int hq = li >> 3, sl = li & 7;
#pragma unroll
    for (int it = 0; it < 2; ++it) {
        const int nl = w*4 + it*2 + half;     // local node 0..15
        const int n  = yy*16 + nl;
        const int s0 = bst[nl] - lo, s1 = bst[nl+1] - lo;
        // pass A: segment max (8-lane split)
        float mx = -3.4e38f;
        for (int i = s0 + sl; i < s1; i += 8) mx = fmaxf(mx, ssh[i*4 + hq]);
        mx = fmaxf(mx, __shfl_xor(mx, 1));
        mx = fmaxf(mx, __shfl_xor(mx, 2));
        mx = fmaxf(mx, __shfl_xor(mx, 4));
        // pass B: exp + denominator; write exp back to LDS (same-wave visibility)
        float den = 0.f;
        for (int i = s0 + sl; i < s1; i += 8) {
            const float ex = __expf(ssh[i*4 + hq] - mx);
            ssh[i*4 + hq] = ex;
            den += ex;
        }
        den += __shfl_xor(den, 1);
        den += __shfl_xor(den, 2);
        den += __shfl_xor(den, 4);
        const float rd = 1.0f / (den + 1e-16f);
        // pass C: weighted aggregation from LDS, scale at end
        float4 acc = make_float4(0.f, 0.f, 0.f, 0.f);
        for (int i = s0; i < s1; ++i) {
            const float ex = ssh[i*4 + hq];
            const int ss = bls[i] & 63;
            const float4 hv = *(const float4*)&hsh[ss*128 + li*4];
            acc.x += hv.x * ex; acc.y += hv.y * ex;
            acc.z += hv.z * ex; acc.w += hv.w * ex;
        }
        acc.x *= rd; acc.y *= rd; acc.z *= rd; acc.w *= rd;
        float e0 = acc.x > 0.f ? acc.x : expm1f(acc.x);
        float e1 = acc.y > 0.f ? acc.y : expm1f(acc.y);
        float e2 = acc.z > 0.f ? acc.z : expm1f(acc.z);
        float e3 = acc.w > 0.f ? acc.w : expm1f(acc.w);
        u16x4 st = { f2bf(e0), f2bf(e1), f2bf(e2), f2bf(e3) };
        *(u16x4*)&xgb[(size_t)b*8192 + n*128 + li*4] = st;
    }
}

// ---------------- K3: fc1 via bf16 MFMA; A pre-ELU'd bf16; split-K partials ------
// grid (64 j-tiles of 32, 8 k-splits of 1024), 256 threads = 4 waves, 2 blocks/CU.
__global__ __launch_bounds__(256) void k3_fc1(
        const u16* __restrict__ xgb, const float* __restrict__ fc1_w,
        float* __restrict__ part)
{
    __shared__ u16 Ash[128*72];
    __shared__ u16 Bsh[32*72];
    const int jb = blockIdx.x, ks = blockIdx.y, t = threadIdx.x;
    const int j0 = jb*32, k0 = ks*1024;
    const int wave = t >> 6, lane = t & 63;
    const int quad = lane >> 4, l16 = lane & 15;
    const int wm = (wave & 1) * 64, wn = (wave >> 1) * 16;

    f32x4 acc[4];
#pragma unroll
    for (int i = 0; i < 4; ++i) acc[i] = (f32x4){0.f, 0.f, 0.f, 0.f};

    const int arow = t >> 1, acol = (t & 1) * 32;   // A: 128 rows x 64 k (bf16 copy)
    const int brow = t >> 3, bcol = (t & 7) * 8;    // B: 32 rows x 64 k (fp32->bf16)

    for (int kc = 0; kc < 1024; kc += 64) {
        if (kc) __syncthreads();
        const u16* ap = xgb + (size_t)arow*FLATD + k0 + kc + acol;
#pragma unroll
        for (int qq = 0; qq < 4; ++qq)
            *(u16x8*)&Ash[arow*72 + acol + qq*8] = *(const u16x8*)(ap + qq*8);
        const float* bp = fc1_w + (size_t)(j0 + brow)*FLATD + k0 + kc + bcol;
        {
            float4 v0 = *(const float4*)(bp);
            float4 v1 = *(const float4*)(bp + 4);
            u16x8 u = { f2bf(v0.x), f2bf(v0.y), f2bf(v0.z), f2bf(v0.w),
                        f2bf(v1.x), f2bf(v1.y), f2bf(v1.z), f2bf(v1.w) };
            *(u16x8*)&Bsh[brow*72 + bcol] = u;
        }
        __syncthreads();
#pragma unroll
        for (int kk = 0; kk < 64; kk += 32) {
            bf16x8 af[4], bfr;
#pragma unroll
            for (int i = 0; i < 4; ++i)
                af[i] = *(const bf16x8*)&Ash[(wm + i*16 + l16)*72 + kk + quad*8];
            bfr = *(const bf16x8*)&Bsh[(wn + l16)*72 + kk + quad*8];
#pragma unroll
            for (int i = 0; i < 4; ++i)
                acc[i] = __builtin_amdgcn_mfma_f32_16x16x32_bf16(af[i], bfr, acc[i], 0, 0, 0);
        }
    }
    // epilogue: D[m = quad*4+r, n = l16]
#pragma unroll
    for (int i = 0; i < 4; ++i) {
        const int n = j0 + wn + l16;
#pragma unroll
        for (int r = 0; r < 4; ++r) {
            const int m = wm + i*16 + quad*4 + r;
            part[(size_t)ks*262144 + (size_t)m*HIDD + n] = acc[i][r];
        }
    }
}

// ---------------- K4: reduce partials + bias + BN + relu + fc2 ----------------
__global__ __launch_bounds__(256) void k4_fc2(
        const float* __restrict__ part, const float* __restrict__ fc1_b,
        const float* __restrict__ bn_g, const float* __restrict__ bn_b,
        const float* __restrict__ fc2_w, const float* __restrict__ fc2_b,
        float* __restrict__ out)
{
    __shared__ float r0[256], r1[256];
    const int b = blockIdx.x, t = threadIdx.x;
    const float inv = 1.0f / sqrtf(1.0f + 1e-5f);
    float p0 = 0.f, p1 = 0.f;
    for (int j = t; j < 2048; j += 256) {
        float hv = 0.f;
#pragma unroll
        for (int s = 0; s < 8; ++s) hv += part[(size_t)s*262144 + (size_t)b*2048 + j];
        float v = (hv + fc1_b[j]) * (bn_g[j] * inv) + bn_b[j];
        v = fmaxf(v, 0.f);
        p0 += v * fc2_w[j];
        p1 += v * fc2_w[2048 + j];
    }
    r0[t] = p0; r1[t] = p1;
    __syncthreads();
    for (int s = 128; s > 0; s >>= 1) {
        if (t < s) { r0[t] += r0[t+s]; r1[t] += r1[t+s]; }
        __syncthreads();
    }
    if (t == 0) {
        out[b*2 + 0] = r0[0] + fc2_b[0];
        out[b*2 + 1] = r1[0] + fc2_b[1];
    }
}

extern "C" void kernel_launch(void* const* d_in, const int* in_sizes, int n_in,
                              void* d_out, int out_size, void* d_ws, size_t ws_size,
                              hipStream_t stream)
{
    const float* x       = (const float*)d_in[0];
    const int*   ei      = (const int*)  d_in[1];
    const float* ea      = (const float*)d_in[2];
    const float* tcn_w   = (const float*)d_in[3];
    const float* tcn_b   = (const float*)d_in[4];
    const float* lin_l_w = (const float*)d_in[5];
    const float* lin_l_b = (const float*)d_in[6];
    const float* lin_e_w = (const float*)d_in[7];
    const float* lin_e_b = (const float*)d_in[8];
    const float* att     = (const float*)d_in[9];
    const float* fc1_w   = (const float*)d_in[10];
    const float* fc1_b   = (const float*)d_in[11];
    const float* bn_g    = (const float*)d_in[12];
    const float* bn_b    = (const float*)d_in[13];
    const float* fc2_w   = (const float*)d_in[14];
    const float* fc2_b   = (const float*)d_in[15];

    float* ws     = (float*)d_ws;
    float* hbuf   = ws + OFF_H;
    float* score  = ws + OFF_SC;
    float* part   = ws + OFF_P;          // aliases score (dead by k3)
    int*   pos    = (int*)(ws + OFF_M);
    u16*   xgb    = (u16*)(ws + OFF_XGB);
    int*   bstart = (int*)(ws + OFF_BK);
    int*   blist  = bstart + 80;
    float* out    = (float*)d_out;

    k0_bucket  <<<1, 256, 0, stream>>>(ei, bstart, blist, pos);
    k1_tcn_linl<<<dim3(BB, 2), 256, 0, stream>>>(x, tcn_w, tcn_b, lin_l_w, lin_l_b, hbuf);
    k2a_scores <<<dim3(BB, 8), 256, 0, stream>>>(hbuf, ei, ea, lin_e_w, lin_e_b, att, pos, score);
    k2c_aggregate<<<dim3(BB, 4), 256, 0, stream>>>(hbuf, score, bstart, blist, xgb);
    k3_fc1     <<<dim3(64, 8), 256, 0, stream>>>(xgb, fc1_w, part);
    k4_fc2     <<<BB, 256, 0, stream>>>(part, fc1_b, bn_g, bn_b, fc2_w, fc2_b, out);
}

// Round 7
// 247.235 us; speedup vs baseline: 3.0438x; 1.0358x over previous
//
#include <hip/hip_runtime.h>
#include <math.h>

#define BB   128   // batch
#define WW   128   // window
#define FIN  64
#define NNODE 64
#define NE   4096
#define EDIM 16
#define NH   4
#define CDIM 32
#define HC   128   // NH*CDIM
#define FLATD 8192
#define HIDD 2048

// ws layout (float offsets)
#define OFF_H    0u         // h[B][64][128]          1,048,576 f  (dead after k2f)
#define OFF_P    1048576u   // fc1 partials [8][128][2048] = 2,097,152 f
#define OFF_XGB  3211264u   // xgat bf16 (ELU applied) [B][8192] u16 = 524,288 f
#define OFF_BK   4259840u   // bucket ints: bstart[80] + blist[4096]

typedef unsigned short u16;
typedef u16    u16x8  __attribute__((ext_vector_type(8)));
typedef u16    u16x4  __attribute__((ext_vector_type(4)));
typedef __bf16 bf16x8 __attribute__((ext_vector_type(8)));
typedef float  f32x4  __attribute__((ext_vector_type(4)));
typedef float  f32x16 __attribute__((ext_vector_type(16)));

__device__ __forceinline__ u16 f2bf(float f) {   // RNE fp32 -> bf16 bits
    unsigned u = __float_as_uint(f);
    u += 0x7fffu + ((u >> 16) & 1u);
    return (u16)(u >> 16);
}
__device__ __forceinline__ void hilo(float v, u16* h, u16* l) {
    u16 hh = f2bf(v);
    float hf = __uint_as_float(((unsigned)hh) << 16);
    *h = hh;
    *l = f2bf(v - hf);
}

// ---------------- K0: bucket edges by destination (graph shared across batch) ----
// blist entry: (e<<12)|(d<<6)|s
__global__ __launch_bounds__(256) void k0_bucket(
        const int* __restrict__ ei, int* __restrict__ bstart, int* __restrict__ blist)
{
    __shared__ int cnt[64];
    __shared__ int cur[65];
    const int t = threadIdx.x;
    if (t < 64) cnt[t] = 0;
    __syncthreads();
    for (int e = t; e < NE; e += 256) atomicAdd(&cnt[ei[NE + e]], 1);
    __syncthreads();
    if (t == 0) {
        int run = 0;
        for (int n = 0; n < 64; ++n) { cur[n] = run; run += cnt[n]; }
        cur[64] = run;
    }
    __syncthreads();
    if (t < 65) bstart[t] = cur[t];
    __syncthreads();
    for (int e = t; e < NE; e += 256) {
        int d = ei[NE + e], s = ei[e];
        int p = atomicAdd(&cur[d], 1);
        blist[p] = (e << 12) | (d << 6) | s;
    }
}

// ---------------- K1: TCN conv1d(k=3,pad=1) + lin_l -> h[b][n][o] ----------------
__global__ __launch_bounds__(256) void k1_tcn_linl(
        const float* __restrict__ x, const float* __restrict__ tcn_w,
        const float* __restrict__ tcn_b, const float* __restrict__ lin_l_w,
        const float* __restrict__ lin_l_b, float* __restrict__ h)
{
    __shared__ float xs[130*65];
    __shared__ float xg[32*132];
    const int b = blockIdx.x, half = blockIdx.y, t = threadIdx.x;
    const int n0 = half * 32;

    for (int idx = t; idx < 8192; idx += 256) {
        int w = idx >> 6, i = idx & 63;
        xs[(w+1)*65 + i] = x[b*8192 + idx];
    }
    if (t < 65) { xs[t] = 0.f; xs[129*65 + t] = 0.f; }
    __syncthreads();

    {   // phase 1: conv
        const int nl = t >> 3;
        const int n  = n0 + nl;
        const int w0 = (t & 7) * 16;
        float acc[16];
        const float tb = tcn_b[n];
#pragma unroll
        for (int j = 0; j < 16; ++j) acc[j] = tb;
        for (int i = 0; i < 64; ++i) {
            const float t0 = tcn_w[n*192 + 3*i + 0];
            const float t1 = tcn_w[n*192 + 3*i + 1];
            const float t2 = tcn_w[n*192 + 3*i + 2];
            float a = xs[(w0+0)*65 + i];
            float c0 = xs[(w0+1)*65 + i];
#pragma unroll
            for (int dw = 0; dw < 16; ++dw) {
                float c = xs[(w0+dw+2)*65 + i];
                acc[dw] += a*t0 + c0*t1 + c*t2;
                a = c0; c0 = c;
            }
        }
#pragma unroll
        for (int dw = 0; dw < 16; ++dw) xg[nl*132 + w0 + dw] = acc[dw];
    }
    __syncthreads();

    {   // phase 2: 2 o x 8 n register tile
        const int o2 = t & 63, ng = t >> 6;
        const int oA = o2, oB = o2 + 64;
        float accA[8], accB[8];
        const float lbA = lin_l_b[oA], lbB = lin_l_b[oB];
#pragma unroll
        for (int j = 0; j < 8; ++j) { accA[j] = lbA; accB[j] = lbB; }
        for (int c = 0; c < 32; ++c) {
            const float4 lwA = *(const float4*)&lin_l_w[oA*128 + c*4];
            const float4 lwB = *(const float4*)&lin_l_w[oB*128 + c*4];
#pragma unroll
            for (int nn = 0; nn < 8; ++nn) {
                const float4 xv = *(const float4*)&xg[(ng*8+nn)*132 + c*4];
                accA[nn] += xv.x*lwA.x + xv.y*lwA.y + xv.z*lwA.z + xv.w*lwA.w;
                accB[nn] += xv.x*lwB.x + xv.y*lwB.y + xv.z*lwB.z + xv.w*lwB.w;
            }
        }
#pragma unroll
        for (int nn = 0; nn < 8; ++nn) {
            const int n = n0 + ng*8 + nn;
            h[(b*64 + n)*128 + oA] = accA[nn];
            h[(b*64 + n)*128 + oB] = accB[nn];
        }
    }
}

// ---------------- K2F: fused scores + softmax + P-build + P@H aggregation --------
// grid (128 b, 2 node-halves of 32), 512 threads = 8 waves, 1 block/CU.
#define CAPF 2560
__global__ __launch_bounds__(512, 1) void k2_fused(
        const float* __restrict__ hbase, const float* __restrict__ ea,
        const float* __restrict__ lin_e_w, const float* __restrict__ lin_e_b,
        const float* __restrict__ att, const int* __restrict__ bstart,
        const int* __restrict__ blist, u16* __restrict__ xgb)
{
    __shared__ float hbuf[64*132];      // h + 0.5*lin_e_b folded       33.8 KB
    __shared__ float scl[CAPF*4];       // scores (then exp) per edge   40.96 KB
    __shared__ float Pm[4][32][68];     // alpha matrix per head        34.8 KB
    __shared__ int   bst[33];
    const int b = blockIdx.x, half = blockIdx.y, t = threadIdx.x;
    const int lane = t & 63, wv = t >> 6, l32 = lane & 31, h5 = lane >> 5;

    // ---- stage ----
    for (int idx = t; idx < 8192; idx += 512) {
        const int o = idx & 127;
        hbuf[(idx>>7)*132 + o] = hbase[(size_t)b*8192 + idx] + 0.5f*lin_e_b[o];
    }
    for (int idx = t; idx < 4*32*68; idx += 512) ((float*)Pm)[idx] = 0.f;
    if (t < 33) bst[t] = bstart[half*32 + t];
    // A-frags (lin_e_w rows = o) hi/lo and att into VGPRs
    bf16x8 Ah[4], Al[4];
#pragma unroll
    for (int mt = 0; mt < 4; ++mt) {
        const float* wp = &lin_e_w[(mt*32 + l32)*16 + h5*8];
        const float4 w0 = *(const float4*)wp;
        const float4 w1 = *(const float4*)(wp + 4);
        u16 th[8], tl[8];
        hilo(w0.x,&th[0],&tl[0]); hilo(w0.y,&th[1],&tl[1]);
        hilo(w0.z,&th[2],&tl[2]); hilo(w0.w,&th[3],&tl[3]);
        hilo(w1.x,&th[4],&tl[4]); hilo(w1.y,&th[5],&tl[5]);
        hilo(w1.z,&th[6],&tl[6]); hilo(w1.w,&th[7],&tl[7]);
        u16x8 vh = { th[0],th[1],th[2],th[3],th[4],th[5],th[6],th[7] };
        u16x8 vl = { tl[0],tl[1],tl[2],tl[3],tl[4],tl[5],tl[6],tl[7] };
        Ah[mt] = *(bf16x8*)&vh;
        Al[mt] = *(bf16x8*)&vl;
    }
    float4 attv[4][4];
#pragma unroll
    for (int mt = 0; mt < 4; ++mt)
#pragma unroll
        for (int g = 0; g < 4; ++g)
            attv[mt][g] = *(const float4*)&att[mt*32 + g*8 + h5*4];
    __syncthreads();

    const int lo = bst[0], cnt = min(bst[32] - lo, CAPF);
    const int gcnt = (cnt + 31) >> 5;

    // ---- phase 1: scores (bucket-ordered edges; hd near-broadcast) ----
    for (int g = wv; g < gcnt; g += 8) {
        const int idx = g*32 + l32;
        const bool valid = idx < cnt;
        const int pk = valid ? blist[lo + idx] : 0;
        const int sn = pk & 63, dd = (pk >> 6) & 63, e = pk >> 12;
        const float* eap = ea + ((size_t)b*NE + e)*16 + h5*8;
        const float4 v0 = *(const float4*)eap;
        const float4 v1 = *(const float4*)(eap + 4);
        u16 bh[8], bl[8];
        hilo(v0.x,&bh[0],&bl[0]); hilo(v0.y,&bh[1],&bl[1]);
        hilo(v0.z,&bh[2],&bl[2]); hilo(v0.w,&bh[3],&bl[3]);
        hilo(v1.x,&bh[4],&bl[4]); hilo(v1.y,&bh[5],&bl[5]);
        hilo(v1.z,&bh[6],&bl[6]); hilo(v1.w,&bh[7],&bl[7]);
        u16x8 vbh = { bh[0],bh[1],bh[2],bh[3],bh[4],bh[5],bh[6],bh[7] };
        u16x8 vbl = { bl[0],bl[1],bl[2],bl[3],bl[4],bl[5],bl[6],bl[7] };
        const bf16x8 Bh = *(bf16x8*)&vbh;
        const bf16x8 Bl = *(bf16x8*)&vbl;
        float hacc[4];
#pragma unroll
        for (int mt = 0; mt < 4; ++mt) {
            f32x16 D = {0.f,0.f,0.f,0.f,0.f,0.f,0.f,0.f,
                        0.f,0.f,0.f,0.f,0.f,0.f,0.f,0.f};
            D = __builtin_amdgcn_mfma_f32_32x32x16_bf16(Al[mt], Bh, D, 0, 0, 0);
            D = __builtin_amdgcn_mfma_f32_32x32x16_bf16(Ah[mt], Bl, D, 0, 0, 0);
            D = __builtin_amdgcn_mfma_f32_32x32x16_bf16(Ah[mt], Bh, D, 0, 0, 0);
            float s = 0.f;
#pragma unroll
            for (int g4 = 0; g4 < 4; ++g4) {
                const int ob = mt*32 + g4*8 + h5*4;
                const float4 hd = *(const float4*)&hbuf[dd*132 + ob];
                const float4 hs = *(const float4*)&hbuf[sn*132 + ob];
                float x0 = hd.x + hs.x + D[g4*4+0];
                float x1 = hd.y + hs.y + D[g4*4+1];
                float x2 = hd.z + hs.z + D[g4*4+2];
                float x3 = hd.w + hs.w + D[g4*4+3];
                x0 = fmaxf(x0, 0.01f*x0); x1 = fmaxf(x1, 0.01f*x1);
                x2 = fmaxf(x2, 0.01f*x2); x3 = fmaxf(x3, 0.01f*x3);
                const float4 a4 = attv[mt][g4];
                s += a4.x*x0 + a4.y*x1 + a4.z*x2 + a4.w*x3;
            }
            hacc[mt] = s;
        }
#pragma unroll
        for (int hh = 0; hh < 4; ++hh)
            hacc[hh] += __shfl_xor(hacc[hh], 32);
        if (h5 == 0 && valid)
            *(float4*)&scl[idx*4] = make_float4(hacc[0], hacc[1], hacc[2], hacc[3]);
    }
    __syncthreads();

    // ---- phase 2: softmax stats + P scatter ----
    {
        const int pair = t >> 2, sub = t & 3;   // 128 pairs = 32 nodes x 4 heads
        const int nl = pair >> 2, hh = pair & 3;
        const int s0 = bst[nl] - lo, s1 = bst[nl+1] - lo;
        float mx = -3.4e38f;
        for (int i = s0 + sub; i < s1; i += 4) mx = fmaxf(mx, scl[i*4 + hh]);
        mx = fmaxf(mx, __shfl_xor(mx, 1));
        mx = fmaxf(mx, __shfl_xor(mx, 2));
        float den = 0.f;
        for (int i = s0 + sub; i < s1; i += 4) {
            const float ex = __expf(scl[i*4 + hh] - mx);
            scl[i*4 + hh] = ex;
            den += ex;
        }
        den += __shfl_xor(den, 1);
        den += __shfl_xor(den, 2);
        const float rd = 1.0f / (den + 1e-16f);
        for (int i = s0 + sub; i < s1; i += 4) {
            const int src = blist[lo + i] & 63;
            atomicAdd(&Pm[hh][nl][src], scl[i*4 + hh] * rd);
        }
    }
    __syncthreads();

    // ---- phase 3: xgat = P @ H per head (hi/lo both operands), ELU, bf16 out ----
    if (wv < 4) {
        const int hh = wv;
        f32x16 D = {0.f,0.f,0.f,0.f,0.f,0.f,0.f,0.f,
                    0.f,0.f,0.f,0.f,0.f,0.f,0.f,0.f};
#pragma unroll
        for (int k0 = 0; k0 < 64; k0 += 16) {
            const float* pp = &Pm[hh][l32][k0 + h5*8];
            const float4 a0 = *(const float4*)pp;
            const float4 a1 = *(const float4*)(pp + 4);
            u16 ph[8], pl[8];
            hilo(a0.x,&ph[0],&pl[0]); hilo(a0.y,&ph[1],&pl[1]);
            hilo(a0.z,&ph[2],&pl[2]); hilo(a0.w,&ph[3],&pl[3]);
            hilo(a1.x,&ph[4],&pl[4]); hilo(a1.y,&ph[5],&pl[5]);
            hilo(a1.z,&ph[6],&pl[6]); hilo(a1.w,&ph[7],&pl[7]);
            u16x8 vph = { ph[0],ph[1],ph[2],ph[3],ph[4],ph[5],ph[6],ph[7] };
            u16x8 vpl = { pl[0],pl[1],pl[2],pl[3],pl[4],pl[5],pl[6],pl[7] };
            u16 hhv[8], hlv[8];
#pragma unroll
            for (int i = 0; i < 8; ++i) {
                const float v = hbuf[(k0 + h5*8 + i)*132 + hh*32 + l32];
                hilo(v, &hhv[i], &hlv[i]);
            }
            u16x8 vhh = { hhv[0],hhv[1],hhv[2],hhv[3],hhv[4],hhv[5],hhv[6],hhv[7] };
            u16x8 vhl = { hlv[0],hlv[1],hlv[2],hlv[3],hlv[4],hlv[5],hlv[6],hlv[7] };
            const bf16x8 Ph = *(bf16x8*)&vph, Pl = *(bf16x8*)&vpl;
            const bf16x8 Hh = *(bf16x8*)&vhh, Hl = *(bf16x8*)&vhl;
            D = __builtin_amdgcn_mfma_f32_32x32x16_bf16(Pl, Hh, D, 0, 0, 0);
            D = __builtin_amdgcn_mfma_f32_32x32x16_bf16(Ph, Hl, D, 0, 0, 0);
            D = __builtin_amdgcn_mfma_f32_32x32x16_bf16(Ph, Hh, D, 0, 0, 0);
        }
        const int c = l32, o = hh*32 + c;
        const float lb2 = 0.5f * lin_e_b[o];
#pragma unroll
        for (int r = 0; r < 16; ++r) {
            const int m = (r & 3) + 8*(r >> 2) + 4*h5;
            const float corr = (bst[m+1] > bst[m]) ? lb2 : 0.f;
            float v = D[r] - corr;
            v = v > 0.f ? v : expm1f(v);
            xgb[(size_t)b*8192 + (half*32 + m)*128 + o] = f2bf(v);
        }
    }
}

// ---------------- K3: fc1 via bf16 MFMA; A pre-ELU'd bf16; split-K partials ------
__global__ __launch_bounds__(256) void k3_fc1(
        const u16* __restrict__ xgb, const float* __restrict__ fc1_w,
        float* __restrict__ part)
{
    __shared__ u16 Ash[128*72];
    __shared__ u16 Bsh[32*72];
    const int jb = blockIdx.x, ks = blockIdx.y, t = threadIdx.x;
    const int j0 = jb*32, k0 = ks*1024;
    const int wave = t >> 6, lane = t & 63;
    const int quad = lane >> 4, l16 = lane & 15;
    const int wm = (wave & 1) * 64, wn = (wave >> 1) * 16;

    f32x4 acc[4];
#pragma unroll
    for (int i = 0; i < 4; ++i) acc[i] = (f32x4){0.f, 0.f, 0.f, 0.f};

    const int arow = t >> 1, acol = (t & 1) * 32;
    const int brow = t >> 3, bcol = (t & 7) * 8;

    for (int kc = 0; kc < 1024; kc += 64) {
        if (kc) __syncthreads();
        const u16* ap = xgb + (size_t)arow*FLATD + k0 + kc + acol;
#pragma unroll
        for (int qq = 0; qq < 4; ++qq)
            *(u16x8*)&Ash[arow*72 + acol + qq*8] = *(const u16x8*)(ap + qq*8);
        const float* bp = fc1_w + (size_t)(j0 + brow)*FLATD + k0 + kc + bcol;
        {
            float4 v0 = *(const float4*)(bp);
            float4 v1 = *(const float4*)(bp + 4);
            u16x8 u = { f2bf(v0.x), f2bf(v0.y), f2bf(v0.z), f2bf(v0.w),
                        f2bf(v1.x), f2bf(v1.y), f2bf(v1.z), f2bf(v1.w) };
            *(u16x8*)&Bsh[brow*72 + bcol] = u;
        }
        __syncthreads();
#pragma unroll
        for (int kk = 0; kk < 64; kk += 32) {
            bf16x8 af[4], bfr;
#pragma unroll
            for (int i = 0; i < 4; ++i)
                af[i] = *(const bf16x8*)&Ash[(wm + i*16 + l16)*72 + kk + quad*8];
            bfr = *(const bf16x8*)&Bsh[(wn + l16)*72 + kk + quad*8];
#pragma unroll
            for (int i = 0; i < 4; ++i)
                acc[i] = __builtin_amdgcn_mfma_f32_16x16x32_bf16(af[i], bfr, acc[i], 0, 0, 0);
        }
    }
#pragma unroll
    for (int i = 0; i < 4; ++i) {
        const int n = j0 + wn + l16;
#pragma unroll
        for (int r = 0; r < 4; ++r) {
            const int m = wm + i*16 + quad*4 + r;
            part[(size_t)ks*262144 + (size_t)m*HIDD + n] = acc[i][r];
        }
    }
}

// ---------------- K4: reduce partials + bias + BN + relu + fc2 ----------------
__global__ __launch_bounds__(256) void k4_fc2(
        const float* __restrict__ part, const float* __restrict__ fc1_b,
        const float* __restrict__ bn_g, const float* __restrict__ bn_b,
        const float* __restrict__ fc2_w, const float* __restrict__ fc2_b,
        float* __restrict__ out)
{
    __shared__ float r0[256], r1[256];
    const int b = blockIdx.x, t = threadIdx.x;
    const float inv = 1.0f / sqrtf(1.0f + 1e-5f);
    float p0 = 0.f, p1 = 0.f;
    for (int j = t; j < 2048; j += 256) {
        float hv = 0.f;
#pragma unroll
        for (int s = 0; s < 8; ++s) hv += part[(size_t)s*262144 + (size_t)b*2048 + j];
        float v = (hv + fc1_b[j]) * (bn_g[j] * inv) + bn_b[j];
        v = fmaxf(v, 0.f);
        p0 += v * fc2_w[j];
        p1 += v * fc2_w[2048 + j];
    }
    r0[t] = p0; r1[t] = p1;
    __syncthreads();
    for (int s = 128; s > 0; s >>= 1) {
        if (t < s) { r0[t] += r0[t+s]; r1[t] += r1[t+s]; }
        __syncthreads();
    }
    if (t == 0) {
        out[b*2 + 0] = r0[0] + fc2_b[0];
        out[b*2 + 1] = r1[0] + fc2_b[1];
    }
}

extern "C" void kernel_launch(void* const* d_in, const int* in_sizes, int n_in,
                              void* d_out, int out_size, void* d_ws, size_t ws_size,
                              hipStream_t stream)
{
    const float* x       = (const float*)d_in[0];
    const int*   ei      = (const int*)  d_in[1];
    const float* ea      = (const float*)d_in[2];
    const float* tcn_w   = (const float*)d_in[3];
    const float* tcn_b   = (const float*)d_in[4];
    const float* lin_l_w = (const float*)d_in[5];
    const float* lin_l_b = (const float*)d_in[6];
    const float* lin_e_w = (const float*)d_in[7];
    const float* lin_e_b = (const float*)d_in[8];
    const float* att     = (const float*)d_in[9];
    const float* fc1_w   = (const float*)d_in[10];
    const float* fc1_b   = (const float*)d_in[11];
    const float* bn_g    = (const float*)d_in[12];
    const float* bn_b    = (const float*)d_in[13];
    const float* fc2_w   = (const float*)d_in[14];
    const float* fc2_b   = (const float*)d_in[15];

    float* ws     = (float*)d_ws;
    float* hbuf   = ws + OFF_H;
    float* part   = ws + OFF_P;
    u16*   xgb    = (u16*)(ws + OFF_XGB);
    int*   bstart = (int*)(ws + OFF_BK);
    int*   blist  = bstart + 80;
    float* out    = (float*)d_out;

    k0_bucket  <<<1, 256, 0, stream>>>(ei, bstart, blist);
    k1_tcn_linl<<<dim3(BB, 2), 256, 0, stream>>>(x, tcn_w, tcn_b, lin_l_w, lin_l_b, hbuf);
    k2_fused   <<<dim3(BB, 2), 512, 0, stream>>>(hbuf, ea, lin_e_w, lin_e_b, att,
                                                 bstart, blist, xgb);
    k3_fc1     <<<dim3(64, 8), 256, 0, stream>>>(xgb, fc1_w, part);
    k4_fc2     <<<BB, 256, 0, stream>>>(part, fc1_b, bn_g, bn_b, fc2_w, fc2_b, out);
}